// Round 1
// baseline (1625.109 us; speedup 1.0000x reference)
//
#include <hip/hip_runtime.h>
#include <cmath>

#define NN 100000
#define NE 800000
#define ETOT (NE + NN)
#define F_IN 300

// ---------------- SGEMM: 128x128 tile, 8x8 per thread, 256 threads ----------
#define BM 128
#define BN 128
#define BK 8
#define TM 8
#define TN 8

__global__ __launch_bounds__(256)
void sgemm_kernel(const float* __restrict__ A, const float* __restrict__ B,
                  const float* __restrict__ bias, float* __restrict__ C,
                  int M, int N, int K, int do_relu)
{
    __shared__ float As[BK][BM + 4];
    __shared__ float Bs[BK][BN + 4];
    const int tid = threadIdx.x;
    const int bm = blockIdx.x * BM;
    const int bn = blockIdx.y * BN;
    const int tr = tid >> 4;   // 0..15 (row group)
    const int tc = tid & 15;   // 0..15 (col group, strided columns tc+16*j)

    const int a_row  = tid >> 1;
    const int a_col0 = (tid & 1) * 4;
    const int b_row  = tid >> 5;
    const int b_col0 = (tid & 31) * 4;

    float acc[TM][TN];
#pragma unroll
    for (int i = 0; i < TM; i++)
#pragma unroll
        for (int j = 0; j < TN; j++) acc[i][j] = 0.f;

    for (int k0 = 0; k0 < K; k0 += BK) {
        float a0 = 0.f, a1 = 0.f, a2 = 0.f, a3 = 0.f;
        int gm = bm + a_row;
        if (gm < M) {
            const float* ap = A + (size_t)gm * K + k0 + a_col0;
            int kr = K - (k0 + a_col0);
            if (kr > 0) a0 = ap[0];
            if (kr > 1) a1 = ap[1];
            if (kr > 2) a2 = ap[2];
            if (kr > 3) a3 = ap[3];
        }
        As[a_col0 + 0][a_row] = a0;
        As[a_col0 + 1][a_row] = a1;
        As[a_col0 + 2][a_row] = a2;
        As[a_col0 + 3][a_row] = a3;

        float b0 = 0.f, b1 = 0.f, b2 = 0.f, b3 = 0.f;
        int gk = k0 + b_row;
        int gn = bn + b_col0;
        if (gk < K && gn < N) {
            const float* bp = B + (size_t)gk * N + gn;
            b0 = bp[0]; b1 = bp[1]; b2 = bp[2]; b3 = bp[3];
        }
        Bs[b_row][b_col0 + 0] = b0;
        Bs[b_row][b_col0 + 1] = b1;
        Bs[b_row][b_col0 + 2] = b2;
        Bs[b_row][b_col0 + 3] = b3;

        __syncthreads();
#pragma unroll
        for (int kk = 0; kk < BK; kk++) {
            float af[TM], bf[TN];
#pragma unroll
            for (int i = 0; i < TM; i++) af[i] = As[kk][tr * TM + i];
#pragma unroll
            for (int j = 0; j < TN; j++) bf[j] = Bs[kk][tc + 16 * j];
#pragma unroll
            for (int i = 0; i < TM; i++)
#pragma unroll
                for (int j = 0; j < TN; j++)
                    acc[i][j] = fmaf(af[i], bf[j], acc[i][j]);
        }
        __syncthreads();
    }

#pragma unroll
    for (int i = 0; i < TM; i++) {
        int gm = bm + tr * TM + i;
        if (gm >= M) continue;
#pragma unroll
        for (int j = 0; j < TN; j++) {
            int gn = bn + tc + 16 * j;
            if (gn >= N) continue;
            float v = acc[i][j];
            if (bias) v += bias[gn];
            if (do_relu) v = fmaxf(v, 0.f);
            C[(size_t)gm * N + gn] = v;
        }
    }
}

// ---------------- CSR build ----------------
__global__ void count_edges(const int* __restrict__ ei, int* __restrict__ counts)
{
    int e = blockIdx.x * blockDim.x + threadIdx.x;
    if (e >= ETOT) return;
    int d = (e < NE) ? ei[NE + e] : (e - NE);
    atomicAdd(&counts[d], 1);
}

__global__ __launch_bounds__(1024)
void scan_counts(int* __restrict__ counts, int* __restrict__ row_ptr)
{
    __shared__ int sh[1024];
    const int tid = threadIdx.x;
    const int chunk = (NN + 1023) / 1024;      // 98
    const int lo = tid * chunk;
    const int hi = min(NN, lo + chunk);
    int s = 0;
    for (int i = lo; i < hi; i++) s += counts[i];
    sh[tid] = s;
    __syncthreads();
    for (int off = 1; off < 1024; off <<= 1) {
        int v = (tid >= off) ? sh[tid - off] : 0;
        __syncthreads();
        sh[tid] += v;
        __syncthreads();
    }
    int run = (tid > 0) ? sh[tid - 1] : 0;
    for (int i = lo; i < hi; i++) {
        int c = counts[i];
        row_ptr[i] = run;
        counts[i] = run;   // becomes cursor for fill
        run += c;
    }
    if (tid == 0) row_ptr[NN] = ETOT;
}

__global__ void fill_edges(const int* __restrict__ ei, int* __restrict__ cursor,
                           int* __restrict__ csr_src)
{
    int e = blockIdx.x * blockDim.x + threadIdx.x;
    if (e >= ETOT) return;
    int s, d;
    if (e < NE) { s = ei[e]; d = ei[NE + e]; }
    else        { s = e - NE; d = s; }
    int pos = atomicAdd(&cursor[d], 1);
    csr_src[pos] = s;
}

// ---------------- small matvec helpers ----------------
// v[i] = sum_j w[i, j] * a[j]   (w: [Cin, Cout] row-major)
__global__ void wv_kernel(const float* __restrict__ w, const float* __restrict__ a,
                          float* __restrict__ v, int Cin, int Cout)
{
    int i = blockIdx.x * blockDim.x + threadIdx.x;
    if (i >= Cin) return;
    float s = 0.f;
    for (int j = 0; j < Cout; j++) s = fmaf(w[(size_t)i * Cout + j], a[j], s);
    v[i] = s;
}

// out[n] = dot(H[n,:], v)   wave per row
__global__ __launch_bounds__(256)
void matvec_kernel(const float* __restrict__ H, const float* __restrict__ v,
                   float* __restrict__ out, int C)
{
    int lane = threadIdx.x & 63;
    int n = blockIdx.x * 4 + (threadIdx.x >> 6);
    if (n >= NN) return;
    const float* row = H + (size_t)n * C;
    float s = 0.f;
    for (int c = lane; c < C; c += 64) s = fmaf(row[c], v[c], s);
#pragma unroll
    for (int off = 32; off; off >>= 1) s += __shfl_xor(s, off);
    if (lane == 0) out[n] = s;
}

// ---------------- GAT attention + aggregation (block = one dst node) --------
__global__ void gat_aggregate(const float* __restrict__ hsrc,
                              const float* __restrict__ a_s,
                              const float* __restrict__ a_d,
                              const int* __restrict__ row_ptr,
                              const int* __restrict__ csr_src,
                              const float* __restrict__ bias,
                              float* __restrict__ out, int C)
{
    const int n = blockIdx.x;
    const int tid = threadIdx.x;
    const int nt = blockDim.x;        // == C (256 or 128)
    const int start = row_ptr[n];
    const int deg = row_ptr[n + 1] - start;

    __shared__ float w_sh[256];
    __shared__ int   s_sh[256];
    __shared__ float red[4];

    const float a_dn = a_d[n];
    const int lane = tid & 63, wvi = tid >> 6, nw = nt >> 6;

    // pass 1: segment max of leaky_relu(a_s[src] + a_d[n])
    float m = -1e30f;
    for (int i = tid; i < deg; i += nt) {
        float e = a_s[csr_src[start + i]] + a_dn;
        e = (e >= 0.f) ? e : 0.2f * e;
        m = fmaxf(m, e);
    }
#pragma unroll
    for (int off = 32; off; off >>= 1) m = fmaxf(m, __shfl_xor(m, off));
    if (lane == 0) red[wvi] = m;
    __syncthreads();
    m = red[0];
    for (int i = 1; i < nw; i++) m = fmaxf(m, red[i]);
    __syncthreads();

    // pass 2: w = exp(e-m); acc[c] += w * hsrc[src, c]; denom = sum w
    float acc = 0.f, dsum = 0.f;
    for (int c0 = 0; c0 < deg; c0 += nt) {
        const int cnt = min(nt, deg - c0);
        if (tid < cnt) {
            int s = csr_src[start + c0 + tid];
            float e = a_s[s] + a_dn;
            e = (e >= 0.f) ? e : 0.2f * e;
            float w = expf(e - m);
            w_sh[tid] = w;
            s_sh[tid] = s;
            dsum += w;
        }
        __syncthreads();
        for (int j = 0; j < cnt; j++)
            acc = fmaf(w_sh[j], hsrc[(size_t)s_sh[j] * C + tid], acc);
        __syncthreads();
    }
#pragma unroll
    for (int off = 32; off; off >>= 1) dsum += __shfl_xor(dsum, off);
    if (lane == 0) red[wvi] = dsum;
    __syncthreads();
    float denom = 0.f;
    for (int i = 0; i < nw; i++) denom += red[i];

    float o = acc / (denom + 1e-16f) + bias[tid];
    out[(size_t)n * C + tid] = fmaxf(o, 0.f);   // both GAT layers have relu after
}

// ---------------- BatchNorm stats + finalize ----------------
__global__ __launch_bounds__(256)
void bn_stats(const float* __restrict__ h, float* __restrict__ stats)
{
    int col = threadIdx.x & 63;
    int rg = threadIdx.x >> 6;
    int r0 = blockIdx.x * 256;
    int r1 = min(r0 + 256, NN);
    float s = 0.f, s2 = 0.f;
    for (int r = r0 + rg; r < r1; r += 4) {
        float v = h[(size_t)r * 64 + col];
        s += v; s2 += v * v;
    }
    __shared__ float sh[2][4][64];
    sh[0][rg][col] = s; sh[1][rg][col] = s2;
    __syncthreads();
    if (rg == 0) {
        s  = sh[0][0][col] + sh[0][1][col] + sh[0][2][col] + sh[0][3][col];
        s2 = sh[1][0][col] + sh[1][1][col] + sh[1][2][col] + sh[1][3][col];
        atomicAdd(&stats[col], s);
        atomicAdd(&stats[64 + col], s2);
    }
}

__global__ void bn_finalize(const float* __restrict__ stats,
                            const float* __restrict__ g, const float* __restrict__ b,
                            float* __restrict__ ss)
{
    int c = threadIdx.x;   // 64 threads
    float mu = stats[c] / (float)NN;
    float var = stats[64 + c] / (float)NN - mu * mu;
    float rs = rsqrtf(var + 1e-5f);
    float sc = rs * g[c];
    ss[c] = sc;
    ss[64 + c] = b[c] - mu * sc;
}

// ---------------- fused BN-apply + relu + fc2 + log_softmax (wave/node) -----
__global__ __launch_bounds__(256)
void final_head(const float* __restrict__ h3, const float* __restrict__ ss,
                const float* __restrict__ fc2_w, const float* __restrict__ fc2_b,
                float* __restrict__ out)
{
    int lane = threadIdx.x & 63;
    int n = blockIdx.x * 4 + (threadIdx.x >> 6);
    if (n >= NN) return;
    float y = h3[(size_t)n * 64 + lane];
    y = fmaxf(y * ss[lane] + ss[64 + lane], 0.f);
    float z[4];
#pragma unroll
    for (int o = 0; o < 4; o++) {
        float p = y * fc2_w[lane * 4 + o];
#pragma unroll
        for (int off = 32; off; off >>= 1) p += __shfl_xor(p, off);
        z[o] = p + fc2_b[o];
    }
    float mx = fmaxf(fmaxf(z[0], z[1]), fmaxf(z[2], z[3]));
    float lse = mx + logf(expf(z[0] - mx) + expf(z[1] - mx) +
                          expf(z[2] - mx) + expf(z[3] - mx));
    if (lane < 4) out[(size_t)n * 4 + lane] = z[lane] - lse;
}

// ---------------- launch ----------------
extern "C" void kernel_launch(void* const* d_in, const int* in_sizes, int n_in,
                              void* d_out, int out_size, void* d_ws, size_t ws_size,
                              hipStream_t stream)
{
    const float* x      = (const float*)d_in[0];
    const int*   ei     = (const int*)d_in[1];
    const float* lin_w  = (const float*)d_in[2];
    const float* lin_b  = (const float*)d_in[3];
    const float* w1_src = (const float*)d_in[4];
    const float* w1_dst = (const float*)d_in[5];
    const float* a1_src = (const float*)d_in[6];
    const float* a1_dst = (const float*)d_in[7];
    const float* b1     = (const float*)d_in[8];
    const float* w2_src = (const float*)d_in[9];
    const float* w2_dst = (const float*)d_in[10];
    const float* a2_src = (const float*)d_in[11];
    const float* a2_dst = (const float*)d_in[12];
    const float* b2     = (const float*)d_in[13];
    const float* fc1_w  = (const float*)d_in[14];
    const float* fc1_b  = (const float*)d_in[15];
    const float* bn_g   = (const float*)d_in[16];
    const float* bn_b   = (const float*)d_in[17];
    const float* fc2_w  = (const float*)d_in[18];
    const float* fc2_b  = (const float*)d_in[19];
    float* out = (float*)d_out;

    // workspace layout (all 4-byte elems): A(25.6M) B(25.6M) C(12.8M) + small
    float* ws = (float*)d_ws;
    const size_t NC1 = (size_t)NN * 256;
    const size_t NC2 = (size_t)NN * 128;
    float* bufA  = ws;                 // h0 -> h1 -> h3
    float* bufB  = bufA + NC1;         // h_src1 -> h_src2
    float* bufC  = bufB + NC1;         // h2
    float* aS    = bufC + NC2;
    float* aD    = aS + NN;
    float* vvec  = aD + NN;
    float* ss    = vvec + 256;
    float* stats = ss + 128;
    int* row_ptr = (int*)(stats + 128);
    int* cursor  = row_ptr + (NN + 1);
    int* csr_src = cursor + (NN + 1);

    const int eb = (ETOT + 255) / 256;

    // CSR build (reused by both GAT layers)
    hipMemsetAsync(cursor, 0, sizeof(int) * NN, stream);
    count_edges<<<eb, 256, 0, stream>>>(ei, cursor);
    scan_counts<<<1, 1024, 0, stream>>>(cursor, row_ptr);
    fill_edges<<<eb, 256, 0, stream>>>(ei, cursor, csr_src);

    const int MB = (NN + BM - 1) / BM;   // 782

    // h0 = relu(x @ lin_w + lin_b)
    sgemm_kernel<<<dim3(MB, 2), 256, 0, stream>>>(x, lin_w, lin_b, bufA, NN, 256, F_IN, 1);

    // ---- GAT layer 1 (256 -> 256) ----
    wv_kernel<<<4, 64, 0, stream>>>(w1_dst, a1_dst, vvec, 256, 256);
    sgemm_kernel<<<dim3(MB, 2), 256, 0, stream>>>(bufA, w1_src, nullptr, bufB, NN, 256, 256, 0);
    matvec_kernel<<<(NN + 3) / 4, 256, 0, stream>>>(bufB, a1_src, aS, 256);
    matvec_kernel<<<(NN + 3) / 4, 256, 0, stream>>>(bufA, vvec, aD, 256);
    gat_aggregate<<<NN, 256, 0, stream>>>(bufB, aS, aD, row_ptr, csr_src, b1, bufA, 256);

    // ---- GAT layer 2 (256 -> 128) ----
    wv_kernel<<<4, 64, 0, stream>>>(w2_dst, a2_dst, vvec, 256, 128);
    sgemm_kernel<<<dim3(MB, 1), 256, 0, stream>>>(bufA, w2_src, nullptr, bufB, NN, 128, 256, 0);
    matvec_kernel<<<(NN + 3) / 4, 256, 0, stream>>>(bufB, a2_src, aS, 128);
    matvec_kernel<<<(NN + 3) / 4, 256, 0, stream>>>(bufA, vvec, aD, 256);
    gat_aggregate<<<NN, 128, 0, stream>>>(bufB, aS, aD, row_ptr, csr_src, b2, bufC, 128);

    // ---- fc1 + BN + relu + fc2 + log_softmax ----
    sgemm_kernel<<<dim3(MB, 1), 256, 0, stream>>>(bufC, fc1_w, fc1_b, bufA, NN, 64, 128, 0);
    hipMemsetAsync(stats, 0, sizeof(float) * 128, stream);
    bn_stats<<<(NN + 255) / 256, 256, 0, stream>>>(bufA, stats);
    bn_finalize<<<1, 64, 0, stream>>>(stats, bn_g, bn_b, ss);
    final_head<<<(NN + 3) / 4, 256, 0, stream>>>(bufA, ss, fc2_w, fc2_b, out);
}

// Round 2
// 1244.228 us; speedup vs baseline: 1.3061x; 1.3061x over previous
//
#include <hip/hip_runtime.h>
#include <hip/hip_bf16.h>
#include <cmath>

#define NN 100000
#define NE 800000
#define ETOT (NE + NN)
#define MP 100096            // 782 * 128, padded row count

typedef __attribute__((ext_vector_type(8))) short bf16x8;
typedef __attribute__((ext_vector_type(4))) float f32x4;

__device__ inline void gl_lds16(const void* g, void* l) {
    __builtin_amdgcn_global_load_lds(
        (const __attribute__((address_space(1))) void*)g,
        (__attribute__((address_space(3))) void*)l, 16, 0, 0);
}

// ---------------- MFMA GEMM: C[M,N] = A[M,Kp] @ Bt[N,Kp]^T ------------------
// 128x128 tile, 4 waves, each wave 64x64 = 4x4 MFMA tiles of 16x16x32 bf16.
// LDS staged via global_load_lds width 16; chunk-XOR swizzle for 2-way-max
// bank aliasing on ds_read_b128 (2-way is free, m136).
// flags: 1 = relu, 2 = bf16 output (else fp32)
__global__ __launch_bounds__(256)
void mfma_gemm(const __hip_bfloat16* __restrict__ Abf,
               const __hip_bfloat16* __restrict__ Btbf,
               const float* __restrict__ bias, void* __restrict__ out,
               int Kp, int ldc, int Mstore, int Nstore, int flags)
{
    __shared__ __align__(16) short As[128 * 32];
    __shared__ __align__(16) short Bs[128 * 32];
    const short* A  = (const short*)Abf;
    const short* Bt = (const short*)Btbf;

    const int tid  = threadIdx.x;
    const int lane = tid & 63;
    const int wv   = tid >> 6;
    const int wr   = (wv >> 1) * 64;
    const int wc   = (wv & 1) * 64;
    const int quad = lane >> 4;
    const int l16  = lane & 15;
    const long bm = (long)blockIdx.x * 128;
    const long bn = (long)blockIdx.y * 128;

    // staging: thread t covers LDS 16B-chunks t and t+256 of each tile.
    // chunk t -> (row r = t>>2, lds chunk c = t&3); global chunk cg = c ^ ((r>>1)&3)
    const int r0 = tid >> 2;
    const int c0 = (tid & 3) ^ ((r0 >> 1) & 3);
    const int r1 = r0 + 64;
    const int c1 = (tid & 3) ^ ((r1 >> 1) & 3);
    const short* a_g0 = A + (bm + r0) * (long)Kp + c0 * 8;
    const short* a_g1 = A + (bm + r1) * (long)Kp + c1 * 8;
    const short* b_g0 = Bt + (bn + r0) * (long)Kp + c0 * 8;
    const short* b_g1 = Bt + (bn + r1) * (long)Kp + c1 * 8;
    short* a_l0 = &As[tid * 8];
    short* a_l1 = &As[(tid + 256) * 8];
    short* b_l0 = &Bs[tid * 8];
    short* b_l1 = &Bs[(tid + 256) * 8];

    f32x4 acc[4][4] = {};
    const int xr = (quad ^ ((l16 >> 1) & 3)) * 8;   // swizzled k-chunk offset

    for (int k0 = 0; k0 < Kp; k0 += 32) {
        gl_lds16(a_g0 + k0, a_l0);
        gl_lds16(a_g1 + k0, a_l1);
        gl_lds16(b_g0 + k0, b_l0);
        gl_lds16(b_g1 + k0, b_l1);
        __syncthreads();

        bf16x8 af[4], bf[4];
#pragma unroll
        for (int i = 0; i < 4; i++)
            af[i] = *(const bf16x8*)&As[(wr + i * 16 + l16) * 32 + xr];
#pragma unroll
        for (int j = 0; j < 4; j++)
            bf[j] = *(const bf16x8*)&Bs[(wc + j * 16 + l16) * 32 + xr];
#pragma unroll
        for (int i = 0; i < 4; i++)
#pragma unroll
            for (int j = 0; j < 4; j++)
                acc[i][j] = __builtin_amdgcn_mfma_f32_16x16x32_bf16(
                    af[i], bf[j], acc[i][j], 0, 0, 0);
        __syncthreads();
    }

    __hip_bfloat16* outb = (__hip_bfloat16*)out;
    float* outf = (float*)out;
#pragma unroll
    for (int i = 0; i < 4; i++) {
        long row_base = bm + wr + i * 16 + quad * 4;
#pragma unroll
        for (int j = 0; j < 4; j++) {
            long col = bn + wc + j * 16 + l16;
            if (col >= Nstore) continue;
            float bv = bias ? bias[col] : 0.f;
#pragma unroll
            for (int r = 0; r < 4; r++) {
                long row = row_base + r;
                if (row >= Mstore) continue;
                float v = acc[i][j][r] + bv;
                if (flags & 1) v = fmaxf(v, 0.f);
                if (flags & 2) outb[row * ldc + col] = __float2bfloat16(v);
                else           outf[row * ldc + col] = v;
            }
        }
    }
}

// ---------------- casts ----------------
// x [NN,300] fp32 -> [MP,320] bf16, zero-padded (k-pad MUST be zero)
__global__ void cast_x(const float* __restrict__ x, __hip_bfloat16* __restrict__ xb)
{
    int row = blockIdx.x;
    int col = threadIdx.x;           // 320 threads
    float v = (row < NN && col < 300) ? x[(size_t)row * 300 + col] : 0.f;
    xb[(size_t)row * 320 + col] = __float2bfloat16(v);
}

// w [K,N] fp32 -> wt [Np,Kp] bf16 transposed, zero-padded
__global__ void cast_wT(const float* __restrict__ w, __hip_bfloat16* __restrict__ wt,
                        int K, int N, int Kp, int Np)
{
    int idx = blockIdx.x * 256 + threadIdx.x;
    if (idx >= Np * Kp) return;
    int n = idx / Kp, k = idx % Kp;
    float v = (n < N && k < K) ? w[(size_t)k * N + n] : 0.f;
    wt[idx] = __float2bfloat16(v);
}

// ---------------- CSR build ----------------
__global__ void count_edges(const int* __restrict__ ei, int* __restrict__ counts)
{
    int e = blockIdx.x * blockDim.x + threadIdx.x;
    if (e >= ETOT) return;
    int d = (e < NE) ? ei[NE + e] : (e - NE);
    atomicAdd(&counts[d], 1);
}

__global__ __launch_bounds__(1024)
void scan_counts(int* __restrict__ counts, int* __restrict__ row_ptr)
{
    __shared__ int sh[1024];
    const int tid = threadIdx.x;
    const int chunk = (NN + 1023) / 1024;
    const int lo = tid * chunk;
    const int hi = min(NN, lo + chunk);
    int s = 0;
    for (int i = lo; i < hi; i++) s += counts[i];
    sh[tid] = s;
    __syncthreads();
    for (int off = 1; off < 1024; off <<= 1) {
        int v = (tid >= off) ? sh[tid - off] : 0;
        __syncthreads();
        sh[tid] += v;
        __syncthreads();
    }
    int run = (tid > 0) ? sh[tid - 1] : 0;
    for (int i = lo; i < hi; i++) {
        int c = counts[i];
        row_ptr[i] = run;
        counts[i] = run;
        run += c;
    }
    if (tid == 0) row_ptr[NN] = ETOT;
}

__global__ void fill_edges(const int* __restrict__ ei, int* __restrict__ cursor,
                           int* __restrict__ csr_src)
{
    int e = blockIdx.x * blockDim.x + threadIdx.x;
    if (e >= ETOT) return;
    int s, d;
    if (e < NE) { s = ei[e]; d = ei[NE + e]; }
    else        { s = e - NE; d = s; }
    int pos = atomicAdd(&cursor[d], 1);
    csr_src[pos] = s;
}

// ---------------- small matvec helpers ----------------
__global__ void wv_kernel(const float* __restrict__ w, const float* __restrict__ a,
                          float* __restrict__ v, int Cin, int Cout)
{
    int i = blockIdx.x * blockDim.x + threadIdx.x;
    if (i >= Cin) return;
    float s = 0.f;
    for (int j = 0; j < Cout; j++) s = fmaf(w[(size_t)i * Cout + j], a[j], s);
    v[i] = s;
}

__global__ __launch_bounds__(256)
void matvec_bf(const __hip_bfloat16* __restrict__ H, const float* __restrict__ v,
               float* __restrict__ out, int C)
{
    int lane = threadIdx.x & 63;
    int n = blockIdx.x * 4 + (threadIdx.x >> 6);
    if (n >= NN) return;
    const __hip_bfloat16* row = H + (size_t)n * C;
    float s = 0.f;
    for (int c = lane; c < C; c += 64) s = fmaf(__bfloat162float(row[c]), v[c], s);
#pragma unroll
    for (int off = 32; off; off >>= 1) s += __shfl_xor(s, off);
    if (lane == 0) out[n] = s;
}

// ---------------- GAT attention + aggregation (block = one dst node) --------
__global__ void gat_aggregate(const __hip_bfloat16* __restrict__ hsrc,
                              const float* __restrict__ a_s,
                              const float* __restrict__ a_d,
                              const int* __restrict__ row_ptr,
                              const int* __restrict__ csr_src,
                              const float* __restrict__ bias,
                              __hip_bfloat16* __restrict__ out, int C)
{
    const int n = blockIdx.x;
    const int tid = threadIdx.x;
    const int nt = blockDim.x;
    const int start = row_ptr[n];
    const int deg = row_ptr[n + 1] - start;

    __shared__ float w_sh[256];
    __shared__ int   s_sh[256];
    __shared__ float red[4];

    const float a_dn = a_d[n];
    const int lane = tid & 63, wvi = tid >> 6, nw = nt >> 6;

    float m = -1e30f;
    for (int i = tid; i < deg; i += nt) {
        float e = a_s[csr_src[start + i]] + a_dn;
        e = (e >= 0.f) ? e : 0.2f * e;
        m = fmaxf(m, e);
    }
#pragma unroll
    for (int off = 32; off; off >>= 1) m = fmaxf(m, __shfl_xor(m, off));
    if (lane == 0) red[wvi] = m;
    __syncthreads();
    m = red[0];
    for (int i = 1; i < nw; i++) m = fmaxf(m, red[i]);
    __syncthreads();

    float acc = 0.f, dsum = 0.f;
    for (int c0 = 0; c0 < deg; c0 += nt) {
        const int cnt = min(nt, deg - c0);
        if (tid < cnt) {
            int s = csr_src[start + c0 + tid];
            float e = a_s[s] + a_dn;
            e = (e >= 0.f) ? e : 0.2f * e;
            float w = expf(e - m);
            w_sh[tid] = w;
            s_sh[tid] = s;
            dsum += w;
        }
        __syncthreads();
        for (int j = 0; j < cnt; j++)
            acc = fmaf(w_sh[j], __bfloat162float(hsrc[(size_t)s_sh[j] * C + tid]), acc);
        __syncthreads();
    }
#pragma unroll
    for (int off = 32; off; off >>= 1) dsum += __shfl_xor(dsum, off);
    if (lane == 0) red[wvi] = dsum;
    __syncthreads();
    float denom = 0.f;
    for (int i = 0; i < nw; i++) denom += red[i];

    float o = acc / (denom + 1e-16f) + bias[tid];
    out[(size_t)n * C + tid] = __float2bfloat16(fmaxf(o, 0.f));
}

// ---------------- BatchNorm stats + finalize ----------------
__global__ __launch_bounds__(256)
void bn_stats(const float* __restrict__ h, float* __restrict__ stats)
{
    int col = threadIdx.x & 63;
    int rg = threadIdx.x >> 6;
    int r0 = blockIdx.x * 256;
    int r1 = min(r0 + 256, NN);
    float s = 0.f, s2 = 0.f;
    for (int r = r0 + rg; r < r1; r += 4) {
        float v = h[(size_t)r * 64 + col];
        s += v; s2 += v * v;
    }
    __shared__ float sh[2][4][64];
    sh[0][rg][col] = s; sh[1][rg][col] = s2;
    __syncthreads();
    if (rg == 0) {
        s  = sh[0][0][col] + sh[0][1][col] + sh[0][2][col] + sh[0][3][col];
        s2 = sh[1][0][col] + sh[1][1][col] + sh[1][2][col] + sh[1][3][col];
        atomicAdd(&stats[col], s);
        atomicAdd(&stats[64 + col], s2);
    }
}

__global__ void bn_finalize(const float* __restrict__ stats,
                            const float* __restrict__ g, const float* __restrict__ b,
                            float* __restrict__ ss)
{
    int c = threadIdx.x;
    float mu = stats[c] / (float)NN;
    float var = stats[64 + c] / (float)NN - mu * mu;
    float rs = rsqrtf(var + 1e-5f);
    float sc = rs * g[c];
    ss[c] = sc;
    ss[64 + c] = b[c] - mu * sc;
}

__global__ __launch_bounds__(256)
void final_head(const float* __restrict__ h3, const float* __restrict__ ss,
                const float* __restrict__ fc2_w, const float* __restrict__ fc2_b,
                float* __restrict__ out)
{
    int lane = threadIdx.x & 63;
    int n = blockIdx.x * 4 + (threadIdx.x >> 6);
    if (n >= NN) return;
    float y = h3[(size_t)n * 64 + lane];
    y = fmaxf(y * ss[lane] + ss[64 + lane], 0.f);
    float z[4];
#pragma unroll
    for (int o = 0; o < 4; o++) {
        float p = y * fc2_w[lane * 4 + o];
#pragma unroll
        for (int off = 32; off; off >>= 1) p += __shfl_xor(p, off);
        z[o] = p + fc2_b[o];
    }
    float mx = fmaxf(fmaxf(z[0], z[1]), fmaxf(z[2], z[3]));
    float lse = mx + logf(expf(z[0] - mx) + expf(z[1] - mx) +
                          expf(z[2] - mx) + expf(z[3] - mx));
    if (lane < 4) out[(size_t)n * 4 + lane] = z[lane] - lse;
}

// ---------------- launch ----------------
extern "C" void kernel_launch(void* const* d_in, const int* in_sizes, int n_in,
                              void* d_out, int out_size, void* d_ws, size_t ws_size,
                              hipStream_t stream)
{
    const float* x      = (const float*)d_in[0];
    const int*   ei     = (const int*)d_in[1];
    const float* lin_w  = (const float*)d_in[2];
    const float* lin_b  = (const float*)d_in[3];
    const float* w1_src = (const float*)d_in[4];
    const float* w1_dst = (const float*)d_in[5];
    const float* a1_src = (const float*)d_in[6];
    const float* a1_dst = (const float*)d_in[7];
    const float* b1     = (const float*)d_in[8];
    const float* w2_src = (const float*)d_in[9];
    const float* w2_dst = (const float*)d_in[10];
    const float* a2_src = (const float*)d_in[11];
    const float* a2_dst = (const float*)d_in[12];
    const float* b2     = (const float*)d_in[13];
    const float* fc1_w  = (const float*)d_in[14];
    const float* fc1_b  = (const float*)d_in[15];
    const float* bn_g   = (const float*)d_in[16];
    const float* bn_b   = (const float*)d_in[17];
    const float* fc2_w  = (const float*)d_in[18];
    const float* fc2_b  = (const float*)d_in[19];
    float* out = (float*)d_out;

    // -------- workspace layout (region reuse) --------
    char* p = (char*)d_ws;
    auto alloc = [&](size_t bytes) { char* r = p; p += (bytes + 255) & ~(size_t)255; return r; };
    char* R1 = alloc((size_t)MP * 320 * 2);   // x_bf  -> hsrc1
    char* R2 = alloc((size_t)MP * 256 * 2);   // h0    -> hsrc2 | h2
    char* R3 = alloc((size_t)MP * 256 * 2);   // h1    -> h3(f32)
    __hip_bfloat16* wlinT = (__hip_bfloat16*)alloc(256 * 320 * 2);
    __hip_bfloat16* w1T   = (__hip_bfloat16*)alloc(256 * 256 * 2);
    __hip_bfloat16* w2T   = (__hip_bfloat16*)alloc(128 * 256 * 2);
    __hip_bfloat16* fc1T  = (__hip_bfloat16*)alloc(128 * 128 * 2);
    float* aS    = (float*)alloc((size_t)NN * 4);
    float* aD    = (float*)alloc((size_t)NN * 4);
    float* vvec  = (float*)alloc(256 * 4);
    float* ss    = (float*)alloc(128 * 4);
    float* stats = (float*)alloc(128 * 4);
    int* row_ptr = (int*)alloc((size_t)(NN + 1) * 4);
    int* cursor  = (int*)alloc((size_t)(NN + 1) * 4);
    int* csr_src = (int*)alloc((size_t)ETOT * 4);

    __hip_bfloat16* x_bf  = (__hip_bfloat16*)R1;
    __hip_bfloat16* hsrc1 = (__hip_bfloat16*)R1;
    __hip_bfloat16* h0    = (__hip_bfloat16*)R2;
    __hip_bfloat16* hsrc2 = (__hip_bfloat16*)R2;
    __hip_bfloat16* h2    = (__hip_bfloat16*)(R2 + (size_t)MP * 128 * 2);
    __hip_bfloat16* h1    = (__hip_bfloat16*)R3;
    float*          h3    = (float*)R3;

    const int eb = (ETOT + 255) / 256;
    const int MB = MP / 128;   // 782

    // CSR build (reused by both GAT layers)
    hipMemsetAsync(cursor, 0, sizeof(int) * NN, stream);
    count_edges<<<eb, 256, 0, stream>>>(ei, cursor);
    scan_counts<<<1, 1024, 0, stream>>>(cursor, row_ptr);
    fill_edges<<<eb, 256, 0, stream>>>(ei, cursor, csr_src);

    // casts
    cast_x<<<MP, 320, 0, stream>>>(x, x_bf);
    cast_wT<<<(256 * 320 + 255) / 256, 256, 0, stream>>>(lin_w, wlinT, 300, 256, 320, 256);
    cast_wT<<<(256 * 256 + 255) / 256, 256, 0, stream>>>(w1_src, w1T, 256, 256, 256, 256);
    cast_wT<<<(128 * 256 + 255) / 256, 256, 0, stream>>>(w2_src, w2T, 256, 128, 256, 128);
    cast_wT<<<(128 * 128 + 255) / 256, 256, 0, stream>>>(fc1_w, fc1T, 128, 64, 128, 128);

    // h0 = relu(x @ lin_w + lin_b)        [bf16 out]
    mfma_gemm<<<dim3(MB, 2), 256, 0, stream>>>(x_bf, wlinT, lin_b, h0, 320, 256, NN, 256, 3);

    // ---- GAT layer 1 (256 -> 256) ----
    wv_kernel<<<4, 64, 0, stream>>>(w1_dst, a1_dst, vvec, 256, 256);
    mfma_gemm<<<dim3(MB, 2), 256, 0, stream>>>(h0, w1T, nullptr, hsrc1, 256, 256, NN, 256, 2);
    matvec_bf<<<(NN + 3) / 4, 256, 0, stream>>>(hsrc1, a1_src, aS, 256);
    matvec_bf<<<(NN + 3) / 4, 256, 0, stream>>>(h0, vvec, aD, 256);
    gat_aggregate<<<NN, 256, 0, stream>>>(hsrc1, aS, aD, row_ptr, csr_src, b1, h1, 256);

    // ---- GAT layer 2 (256 -> 128) ----
    wv_kernel<<<4, 64, 0, stream>>>(w2_dst, a2_dst, vvec, 256, 128);
    mfma_gemm<<<dim3(MB, 1), 256, 0, stream>>>(h1, w2T, nullptr, hsrc2, 256, 128, NN, 128, 2);
    matvec_bf<<<(NN + 3) / 4, 256, 0, stream>>>(hsrc2, a2_src, aS, 128);
    matvec_bf<<<(NN + 3) / 4, 256, 0, stream>>>(h1, vvec, aD, 256);
    gat_aggregate<<<NN, 128, 0, stream>>>(hsrc2, aS, aD, row_ptr, csr_src, b2, h2, 128);

    // ---- fc1 + BN + relu + fc2 + log_softmax ----
    mfma_gemm<<<dim3(MB, 1), 256, 0, stream>>>(h2, fc1T, fc1_b, h3, 128, 64, NN, 64, 0);
    hipMemsetAsync(stats, 0, sizeof(float) * 128, stream);
    bn_stats<<<(NN + 255) / 256, 256, 0, stream>>>(h3, stats);
    bn_finalize<<<1, 64, 0, stream>>>(stats, bn_g, bn_b, ss);
    final_head<<<(NN + 3) / 4, 256, 0, stream>>>(h3, ss, fc2_w, fc2_b, out);
}

// Round 3
// 1023.532 us; speedup vs baseline: 1.5877x; 1.2156x over previous
//
#include <hip/hip_runtime.h>
#include <hip/hip_bf16.h>
#include <cmath>

#define NN 100000
#define NE 800000
#define ETOT (NE + NN)
#define MP 100096            // 782 * 128, padded row count

#define SCHUNK 512
#define NBLK ((NN + SCHUNK - 1) / SCHUNK)   // 196

typedef __attribute__((ext_vector_type(8))) short bf16x8;
typedef __attribute__((ext_vector_type(4))) float f32x4;

__device__ inline void gl_lds16(const void* g, void* l) {
    __builtin_amdgcn_global_load_lds(
        (const __attribute__((address_space(1))) void*)g,
        (__attribute__((address_space(3))) void*)l, 16, 0, 0);
}

// ---------------- MFMA GEMM: C[M,N] = A[M,Kp] @ Bt[N,Kp]^T ------------------
// 128x128 tile, 4 waves, each wave 64x64 = 4x4 MFMA tiles of 16x16x32 bf16.
// flags: 1 = relu, 2 = bf16 output (else fp32)
__global__ __launch_bounds__(256)
void mfma_gemm(const __hip_bfloat16* __restrict__ Abf,
               const __hip_bfloat16* __restrict__ Btbf,
               const float* __restrict__ bias, void* __restrict__ out,
               int Kp, int ldc, int Mstore, int Nstore, int flags)
{
    __shared__ __align__(16) short As[128 * 32];
    __shared__ __align__(16) short Bs[128 * 32];
    const short* A  = (const short*)Abf;
    const short* Bt = (const short*)Btbf;

    const int tid  = threadIdx.x;
    const int lane = tid & 63;
    const int wv   = tid >> 6;
    const int wr   = (wv >> 1) * 64;
    const int wc   = (wv & 1) * 64;
    const int quad = lane >> 4;
    const int l16  = lane & 15;
    const long bm = (long)blockIdx.x * 128;
    const long bn = (long)blockIdx.y * 128;

    const int r0 = tid >> 2;
    const int c0 = (tid & 3) ^ ((r0 >> 1) & 3);
    const int r1 = r0 + 64;
    const int c1 = (tid & 3) ^ ((r1 >> 1) & 3);
    const short* a_g0 = A + (bm + r0) * (long)Kp + c0 * 8;
    const short* a_g1 = A + (bm + r1) * (long)Kp + c1 * 8;
    const short* b_g0 = Bt + (bn + r0) * (long)Kp + c0 * 8;
    const short* b_g1 = Bt + (bn + r1) * (long)Kp + c1 * 8;
    short* a_l0 = &As[tid * 8];
    short* a_l1 = &As[(tid + 256) * 8];
    short* b_l0 = &Bs[tid * 8];
    short* b_l1 = &Bs[(tid + 256) * 8];

    f32x4 acc[4][4] = {};
    const int xr = (quad ^ ((l16 >> 1) & 3)) * 8;

    for (int k0 = 0; k0 < Kp; k0 += 32) {
        gl_lds16(a_g0 + k0, a_l0);
        gl_lds16(a_g1 + k0, a_l1);
        gl_lds16(b_g0 + k0, b_l0);
        gl_lds16(b_g1 + k0, b_l1);
        __syncthreads();

        bf16x8 af[4], bf[4];
#pragma unroll
        for (int i = 0; i < 4; i++)
            af[i] = *(const bf16x8*)&As[(wr + i * 16 + l16) * 32 + xr];
#pragma unroll
        for (int j = 0; j < 4; j++)
            bf[j] = *(const bf16x8*)&Bs[(wc + j * 16 + l16) * 32 + xr];
#pragma unroll
        for (int i = 0; i < 4; i++)
#pragma unroll
            for (int j = 0; j < 4; j++)
                acc[i][j] = __builtin_amdgcn_mfma_f32_16x16x32_bf16(
                    af[i], bf[j], acc[i][j], 0, 0, 0);
        __syncthreads();
    }

    __hip_bfloat16* outb = (__hip_bfloat16*)out;
    float* outf = (float*)out;
#pragma unroll
    for (int i = 0; i < 4; i++) {
        long row_base = bm + wr + i * 16 + quad * 4;
#pragma unroll
        for (int j = 0; j < 4; j++) {
            long col = bn + wc + j * 16 + l16;
            if (col >= Nstore) continue;
            float bv = bias ? bias[col] : 0.f;
#pragma unroll
            for (int r = 0; r < 4; r++) {
                long row = row_base + r;
                if (row >= Mstore) continue;
                float v = acc[i][j][r] + bv;
                if (flags & 1) v = fmaxf(v, 0.f);
                if (flags & 2) outb[row * ldc + col] = __float2bfloat16(v);
                else           outf[row * ldc + col] = v;
            }
        }
    }
}

// ---------------- casts ----------------
__global__ void cast_x(const float* __restrict__ x, __hip_bfloat16* __restrict__ xb)
{
    int row = blockIdx.x;
    int col = threadIdx.x;           // 320 threads
    float v = (row < NN && col < 300) ? x[(size_t)row * 300 + col] : 0.f;
    xb[(size_t)row * 320 + col] = __float2bfloat16(v);
}

__global__ void cast_wT(const float* __restrict__ w, __hip_bfloat16* __restrict__ wt,
                        int K, int N, int Kp, int Np)
{
    int idx = blockIdx.x * 256 + threadIdx.x;
    if (idx >= Np * Kp) return;
    int n = idx / Kp, k = idx % Kp;
    float v = (n < N && k < K) ? w[(size_t)k * N + n] : 0.f;
    wt[idx] = __float2bfloat16(v);
}

// ---------------- CSR build ----------------
__global__ void count_edges(const int* __restrict__ ei, int* __restrict__ counts)
{
    int e = blockIdx.x * blockDim.x + threadIdx.x;
    if (e >= ETOT) return;
    int d = (e < NE) ? ei[NE + e] : (e - NE);
    atomicAdd(&counts[d], 1);
}

// phase 1: per-block (512-elem) sums
__global__ __launch_bounds__(256)
void scan_partial(const int* __restrict__ counts, int* __restrict__ blk)
{
    __shared__ int sh[256];
    const int tid = threadIdx.x;
    const int base = blockIdx.x * SCHUNK + tid * 2;
    int c0 = (base < NN)     ? counts[base]     : 0;
    int c1 = (base + 1 < NN) ? counts[base + 1] : 0;
    sh[tid] = c0 + c1;
    __syncthreads();
    for (int off = 128; off; off >>= 1) {
        if (tid < off) sh[tid] += sh[tid + off];
        __syncthreads();
    }
    if (tid == 0) blk[blockIdx.x] = sh[0];
}

// phase 2: exclusive scan of NBLK (<=256) block sums, single tiny block
__global__ __launch_bounds__(256)
void scan_blocks(int* __restrict__ blk)
{
    __shared__ int sh[256];
    const int tid = threadIdx.x;
    int v = (tid < NBLK) ? blk[tid] : 0;
    sh[tid] = v;
    __syncthreads();
    for (int off = 1; off < 256; off <<= 1) {
        int u = (tid >= off) ? sh[tid - off] : 0;
        __syncthreads();
        sh[tid] += u;
        __syncthreads();
    }
    if (tid < NBLK) blk[tid] = sh[tid] - v;   // exclusive
}

// phase 3: block-local exclusive scan + global offset -> row_ptr, cursor
__global__ __launch_bounds__(256)
void scan_fill(const int* __restrict__ counts, const int* __restrict__ blk,
               int* __restrict__ row_ptr, int* __restrict__ cursor)
{
    __shared__ int sh[256];
    const int tid = threadIdx.x;
    const int i0 = blockIdx.x * SCHUNK + tid * 2;
    int c0 = (i0 < NN)     ? counts[i0]     : 0;
    int c1 = (i0 + 1 < NN) ? counts[i0 + 1] : 0;
    int s = c0 + c1;
    sh[tid] = s;
    __syncthreads();
    for (int off = 1; off < 256; off <<= 1) {
        int u = (tid >= off) ? sh[tid - off] : 0;
        __syncthreads();
        sh[tid] += u;
        __syncthreads();
    }
    int pre = sh[tid] - s + blk[blockIdx.x];   // exclusive prefix for i0
    if (i0 < NN)     { row_ptr[i0] = pre;          cursor[i0] = pre; }
    if (i0 + 1 < NN) { row_ptr[i0 + 1] = pre + c0; cursor[i0 + 1] = pre + c0; }
    if (blockIdx.x == 0 && tid == 0) row_ptr[NN] = ETOT;
}

__global__ void fill_edges(const int* __restrict__ ei, int* __restrict__ cursor,
                           int* __restrict__ csr_src)
{
    int e = blockIdx.x * blockDim.x + threadIdx.x;
    if (e >= ETOT) return;
    int s, d;
    if (e < NE) { s = ei[e]; d = ei[NE + e]; }
    else        { s = e - NE; d = s; }
    int pos = atomicAdd(&cursor[d], 1);
    csr_src[pos] = s;
}

// ---------------- small matvec helpers ----------------
__global__ void wv_kernel(const float* __restrict__ w, const float* __restrict__ a,
                          float* __restrict__ v, int Cin, int Cout)
{
    int i = blockIdx.x * blockDim.x + threadIdx.x;
    if (i >= Cin) return;
    float s = 0.f;
    for (int j = 0; j < Cout; j++) s = fmaf(w[(size_t)i * Cout + j], a[j], s);
    v[i] = s;
}

__global__ __launch_bounds__(256)
void matvec_bf(const __hip_bfloat16* __restrict__ H, const float* __restrict__ v,
               float* __restrict__ out, int C)
{
    int lane = threadIdx.x & 63;
    int n = blockIdx.x * 4 + (threadIdx.x >> 6);
    if (n >= NN) return;
    const __hip_bfloat16* row = H + (size_t)n * C;
    float s = 0.f;
    for (int c = lane; c < C; c += 64) s = fmaf(__bfloat162float(row[c]), v[c], s);
#pragma unroll
    for (int off = 32; off; off >>= 1) s += __shfl_xor(s, off);
    if (lane == 0) out[n] = s;
}

// ---------------- GAT attention + aggregation (block = one dst node) --------
__global__ void gat_aggregate(const __hip_bfloat16* __restrict__ hsrc,
                              const float* __restrict__ a_s,
                              const float* __restrict__ a_d,
                              const int* __restrict__ row_ptr,
                              const int* __restrict__ csr_src,
                              const float* __restrict__ bias,
                              __hip_bfloat16* __restrict__ out, int C)
{
    const int n = blockIdx.x;
    const int tid = threadIdx.x;
    const int nt = blockDim.x;
    const int start = row_ptr[n];
    const int deg = row_ptr[n + 1] - start;

    __shared__ float w_sh[256];
    __shared__ int   s_sh[256];
    __shared__ float red[4];

    const float a_dn = a_d[n];
    const int lane = tid & 63, wvi = tid >> 6, nw = nt >> 6;

    float m = -1e30f;
    for (int i = tid; i < deg; i += nt) {
        float e = a_s[csr_src[start + i]] + a_dn;
        e = (e >= 0.f) ? e : 0.2f * e;
        m = fmaxf(m, e);
    }
#pragma unroll
    for (int off = 32; off; off >>= 1) m = fmaxf(m, __shfl_xor(m, off));
    if (lane == 0) red[wvi] = m;
    __syncthreads();
    m = red[0];
    for (int i = 1; i < nw; i++) m = fmaxf(m, red[i]);
    __syncthreads();

    float acc = 0.f, dsum = 0.f;
    for (int c0 = 0; c0 < deg; c0 += nt) {
        const int cnt = min(nt, deg - c0);
        if (tid < cnt) {
            int s = csr_src[start + c0 + tid];
            float e = a_s[s] + a_dn;
            e = (e >= 0.f) ? e : 0.2f * e;
            float w = expf(e - m);
            w_sh[tid] = w;
            s_sh[tid] = s;
            dsum += w;
        }
        __syncthreads();
        for (int j = 0; j < cnt; j++)
            acc = fmaf(w_sh[j], __bfloat162float(hsrc[(size_t)s_sh[j] * C + tid]), acc);
        __syncthreads();
    }
#pragma unroll
    for (int off = 32; off; off >>= 1) dsum += __shfl_xor(dsum, off);
    if (lane == 0) red[wvi] = dsum;
    __syncthreads();
    float denom = 0.f;
    for (int i = 0; i < nw; i++) denom += red[i];

    float o = acc / (denom + 1e-16f) + bias[tid];
    out[(size_t)n * C + tid] = __float2bfloat16(fmaxf(o, 0.f));
}

// ---------------- BatchNorm stats + finalize ----------------
__global__ __launch_bounds__(256)
void bn_stats(const float* __restrict__ h, float* __restrict__ stats)
{
    int col = threadIdx.x & 63;
    int rg = threadIdx.x >> 6;
    int r0 = blockIdx.x * 256;
    int r1 = min(r0 + 256, NN);
    float s = 0.f, s2 = 0.f;
    for (int r = r0 + rg; r < r1; r += 4) {
        float v = h[(size_t)r * 64 + col];
        s += v; s2 += v * v;
    }
    __shared__ float sh[2][4][64];
    sh[0][rg][col] = s; sh[1][rg][col] = s2;
    __syncthreads();
    if (rg == 0) {
        s  = sh[0][0][col] + sh[0][1][col] + sh[0][2][col] + sh[0][3][col];
        s2 = sh[1][0][col] + sh[1][1][col] + sh[1][2][col] + sh[1][3][col];
        atomicAdd(&stats[col], s);
        atomicAdd(&stats[64 + col], s2);
    }
}

__global__ void bn_finalize(const float* __restrict__ stats,
                            const float* __restrict__ g, const float* __restrict__ b,
                            float* __restrict__ ss)
{
    int c = threadIdx.x;
    float mu = stats[c] / (float)NN;
    float var = stats[64 + c] / (float)NN - mu * mu;
    float rs = rsqrtf(var + 1e-5f);
    float sc = rs * g[c];
    ss[c] = sc;
    ss[64 + c] = b[c] - mu * sc;
}

__global__ __launch_bounds__(256)
void final_head(const float* __restrict__ h3, const float* __restrict__ ss,
                const float* __restrict__ fc2_w, const float* __restrict__ fc2_b,
                float* __restrict__ out)
{
    int lane = threadIdx.x & 63;
    int n = blockIdx.x * 4 + (threadIdx.x >> 6);
    if (n >= NN) return;
    float y = h3[(size_t)n * 64 + lane];
    y = fmaxf(y * ss[lane] + ss[64 + lane], 0.f);
    float z[4];
#pragma unroll
    for (int o = 0; o < 4; o++) {
        float p = y * fc2_w[lane * 4 + o];
#pragma unroll
        for (int off = 32; off; off >>= 1) p += __shfl_xor(p, off);
        z[o] = p + fc2_b[o];
    }
    float mx = fmaxf(fmaxf(z[0], z[1]), fmaxf(z[2], z[3]));
    float lse = mx + logf(expf(z[0] - mx) + expf(z[1] - mx) +
                          expf(z[2] - mx) + expf(z[3] - mx));
    if (lane < 4) out[(size_t)n * 4 + lane] = z[lane] - lse;
}

// ---------------- launch ----------------
extern "C" void kernel_launch(void* const* d_in, const int* in_sizes, int n_in,
                              void* d_out, int out_size, void* d_ws, size_t ws_size,
                              hipStream_t stream)
{
    const float* x      = (const float*)d_in[0];
    const int*   ei     = (const int*)d_in[1];
    const float* lin_w  = (const float*)d_in[2];
    const float* lin_b  = (const float*)d_in[3];
    const float* w1_src = (const float*)d_in[4];
    const float* w1_dst = (const float*)d_in[5];
    const float* a1_src = (const float*)d_in[6];
    const float* a1_dst = (const float*)d_in[7];
    const float* b1     = (const float*)d_in[8];
    const float* w2_src = (const float*)d_in[9];
    const float* w2_dst = (const float*)d_in[10];
    const float* a2_src = (const float*)d_in[11];
    const float* a2_dst = (const float*)d_in[12];
    const float* b2     = (const float*)d_in[13];
    const float* fc1_w  = (const float*)d_in[14];
    const float* fc1_b  = (const float*)d_in[15];
    const float* bn_g   = (const float*)d_in[16];
    const float* bn_b   = (const float*)d_in[17];
    const float* fc2_w  = (const float*)d_in[18];
    const float* fc2_b  = (const float*)d_in[19];
    float* out = (float*)d_out;

    // -------- workspace layout (region reuse) --------
    char* p = (char*)d_ws;
    auto alloc = [&](size_t bytes) { char* r = p; p += (bytes + 255) & ~(size_t)255; return r; };
    char* R1 = alloc((size_t)MP * 320 * 2);   // x_bf  -> hsrc1
    char* R2 = alloc((size_t)MP * 256 * 2);   // h0    -> hsrc2 | h2
    char* R3 = alloc((size_t)MP * 256 * 2);   // h1    -> h3(f32)
    __hip_bfloat16* wlinT = (__hip_bfloat16*)alloc(256 * 320 * 2);
    __hip_bfloat16* w1T   = (__hip_bfloat16*)alloc(256 * 256 * 2);
    __hip_bfloat16* w2T   = (__hip_bfloat16*)alloc(128 * 256 * 2);
    __hip_bfloat16* fc1T  = (__hip_bfloat16*)alloc(128 * 128 * 2);
    float* aS    = (float*)alloc((size_t)NN * 4);
    float* aD    = (float*)alloc((size_t)NN * 4);
    float* vvec  = (float*)alloc(256 * 4);
    float* ss    = (float*)alloc(128 * 4);
    float* stats = (float*)alloc(128 * 4);
    int* row_ptr = (int*)alloc((size_t)(NN + 1) * 4);
    int* cursor  = (int*)alloc((size_t)(NN + 1) * 4);
    int* counts  = (int*)alloc((size_t)NN * 4);
    int* blk     = (int*)alloc(256 * 4);
    int* csr_src = (int*)alloc((size_t)ETOT * 4);

    __hip_bfloat16* x_bf  = (__hip_bfloat16*)R1;
    __hip_bfloat16* hsrc1 = (__hip_bfloat16*)R1;
    __hip_bfloat16* h0    = (__hip_bfloat16*)R2;
    __hip_bfloat16* hsrc2 = (__hip_bfloat16*)R2;
    __hip_bfloat16* h2    = (__hip_bfloat16*)(R2 + (size_t)MP * 128 * 2);
    __hip_bfloat16* h1    = (__hip_bfloat16*)R3;
    float*          h3    = (float*)R3;

    const int eb = (ETOT + 255) / 256;
    const int MB = MP / 128;   // 782

    // CSR build (parallel 3-phase scan; reused by both GAT layers)
    hipMemsetAsync(counts, 0, sizeof(int) * NN, stream);
    count_edges<<<eb, 256, 0, stream>>>(ei, counts);
    scan_partial<<<NBLK, 256, 0, stream>>>(counts, blk);
    scan_blocks<<<1, 256, 0, stream>>>(blk);
    scan_fill<<<NBLK, 256, 0, stream>>>(counts, blk, row_ptr, cursor);
    fill_edges<<<eb, 256, 0, stream>>>(ei, cursor, csr_src);

    // casts
    cast_x<<<MP, 320, 0, stream>>>(x, x_bf);
    cast_wT<<<(256 * 320 + 255) / 256, 256, 0, stream>>>(lin_w, wlinT, 300, 256, 320, 256);
    cast_wT<<<(256 * 256 + 255) / 256, 256, 0, stream>>>(w1_src, w1T, 256, 256, 256, 256);
    cast_wT<<<(128 * 256 + 255) / 256, 256, 0, stream>>>(w2_src, w2T, 256, 128, 256, 128);
    cast_wT<<<(128 * 128 + 255) / 256, 256, 0, stream>>>(fc1_w, fc1T, 128, 64, 128, 128);

    // h0 = relu(x @ lin_w + lin_b)        [bf16 out]
    mfma_gemm<<<dim3(MB, 2), 256, 0, stream>>>(x_bf, wlinT, lin_b, h0, 320, 256, NN, 256, 3);

    // ---- GAT layer 1 (256 -> 256) ----
    wv_kernel<<<4, 64, 0, stream>>>(w1_dst, a1_dst, vvec, 256, 256);
    mfma_gemm<<<dim3(MB, 2), 256, 0, stream>>>(h0, w1T, nullptr, hsrc1, 256, 256, NN, 256, 2);
    matvec_bf<<<(NN + 3) / 4, 256, 0, stream>>>(hsrc1, a1_src, aS, 256);
    matvec_bf<<<(NN + 3) / 4, 256, 0, stream>>>(h0, vvec, aD, 256);
    gat_aggregate<<<NN, 256, 0, stream>>>(hsrc1, aS, aD, row_ptr, csr_src, b1, h1, 256);

    // ---- GAT layer 2 (256 -> 128) ----
    wv_kernel<<<4, 64, 0, stream>>>(w2_dst, a2_dst, vvec, 256, 128);
    mfma_gemm<<<dim3(MB, 1), 256, 0, stream>>>(h1, w2T, nullptr, hsrc2, 256, 128, NN, 128, 2);
    matvec_bf<<<(NN + 3) / 4, 256, 0, stream>>>(hsrc2, a2_src, aS, 128);
    matvec_bf<<<(NN + 3) / 4, 256, 0, stream>>>(h1, vvec, aD, 256);
    gat_aggregate<<<NN, 128, 0, stream>>>(hsrc2, aS, aD, row_ptr, csr_src, b2, h2, 128);

    // ---- fc1 + BN + relu + fc2 + log_softmax ----
    mfma_gemm<<<dim3(MB, 1), 256, 0, stream>>>(h2, fc1T, fc1_b, h3, 128, 64, NN, 64, 0);
    hipMemsetAsync(stats, 0, sizeof(float) * 128, stream);
    bn_stats<<<(NN + 255) / 256, 256, 0, stream>>>(h3, stats);
    bn_finalize<<<1, 64, 0, stream>>>(stats, bn_g, bn_b, ss);
    final_head<<<(NN + 3) / 4, 256, 0, stream>>>(h3, ss, fc2_w, fc2_b, out);
}

// Round 4
// 817.690 us; speedup vs baseline: 1.9874x; 1.2517x over previous
//
#include <hip/hip_runtime.h>
#include <hip/hip_bf16.h>
#include <cmath>

#define NN 100000
#define NE 800000
#define ETOT (NE + NN)
#define MP 100096            // 782 * 128, padded row count

#define SCHUNK 512
#define NBLK ((NN + SCHUNK - 1) / SCHUNK)   // 196

typedef __attribute__((ext_vector_type(8))) short bf16x8;
typedef __attribute__((ext_vector_type(4))) float f32x4;

__device__ inline void gl_lds16(const void* g, void* l) {
    __builtin_amdgcn_global_load_lds(
        (const __attribute__((address_space(1))) void*)g,
        (__attribute__((address_space(3))) void*)l, 16, 0, 0);
}

// ---------------- MFMA GEMM: C[M,N] = A[M,Kp] @ Bt[N,Kp]^T ------------------
// 128x128 tile, 4 waves, each wave 64x64 = 4x4 MFMA tiles of 16x16x32 bf16.
// flags: 1 = relu, 2 = bf16 output (else fp32)
// Optional fused row-dot: dotout[row] += sum_col v[row,col]*dotv[col]
// (v = post-bias/relu value). Used to fuse the attention matvecs.
__global__ __launch_bounds__(256)
void mfma_gemm(const __hip_bfloat16* __restrict__ Abf,
               const __hip_bfloat16* __restrict__ Btbf,
               const float* __restrict__ bias, void* __restrict__ out,
               const float* __restrict__ dotv, float* __restrict__ dotout,
               int Kp, int ldc, int Mstore, int Nstore, int flags)
{
    __shared__ __align__(16) short As[128 * 32];
    __shared__ __align__(16) short Bs[128 * 32];
    const short* A  = (const short*)Abf;
    const short* Bt = (const short*)Btbf;

    const int tid  = threadIdx.x;
    const int lane = tid & 63;
    const int wv   = tid >> 6;
    const int wr   = (wv >> 1) * 64;
    const int wc   = (wv & 1) * 64;
    const int quad = lane >> 4;
    const int l16  = lane & 15;
    const long bm = (long)blockIdx.x * 128;
    const long bn = (long)blockIdx.y * 128;

    const int r0 = tid >> 2;
    const int c0 = (tid & 3) ^ ((r0 >> 1) & 3);
    const int r1 = r0 + 64;
    const int c1 = (tid & 3) ^ ((r1 >> 1) & 3);
    const short* a_g0 = A + (bm + r0) * (long)Kp + c0 * 8;
    const short* a_g1 = A + (bm + r1) * (long)Kp + c1 * 8;
    const short* b_g0 = Bt + (bn + r0) * (long)Kp + c0 * 8;
    const short* b_g1 = Bt + (bn + r1) * (long)Kp + c1 * 8;
    short* a_l0 = &As[tid * 8];
    short* a_l1 = &As[(tid + 256) * 8];
    short* b_l0 = &Bs[tid * 8];
    short* b_l1 = &Bs[(tid + 256) * 8];

    f32x4 acc[4][4] = {};
    const int xr = (quad ^ ((l16 >> 1) & 3)) * 8;

    for (int k0 = 0; k0 < Kp; k0 += 32) {
        gl_lds16(a_g0 + k0, a_l0);
        gl_lds16(a_g1 + k0, a_l1);
        gl_lds16(b_g0 + k0, b_l0);
        gl_lds16(b_g1 + k0, b_l1);
        __syncthreads();

        bf16x8 af[4], bf[4];
#pragma unroll
        for (int i = 0; i < 4; i++)
            af[i] = *(const bf16x8*)&As[(wr + i * 16 + l16) * 32 + xr];
#pragma unroll
        for (int j = 0; j < 4; j++)
            bf[j] = *(const bf16x8*)&Bs[(wc + j * 16 + l16) * 32 + xr];
#pragma unroll
        for (int i = 0; i < 4; i++)
#pragma unroll
            for (int j = 0; j < 4; j++)
                acc[i][j] = __builtin_amdgcn_mfma_f32_16x16x32_bf16(
                    af[i], bf[j], acc[i][j], 0, 0, 0);
        __syncthreads();
    }

    __hip_bfloat16* outb = (__hip_bfloat16*)out;
    float* outf = (float*)out;
    float dp[16];
#pragma unroll
    for (int t = 0; t < 16; t++) dp[t] = 0.f;

#pragma unroll
    for (int i = 0; i < 4; i++) {
        long row_base = bm + wr + i * 16 + quad * 4;
#pragma unroll
        for (int j = 0; j < 4; j++) {
            long col = bn + wc + j * 16 + l16;
            if (col >= Nstore) continue;
            float bv = bias ? bias[col] : 0.f;
            float dv = dotout ? dotv[col] : 0.f;
#pragma unroll
            for (int r = 0; r < 4; r++) {
                long row = row_base + r;
                float v = acc[i][j][r] + bv;
                if (flags & 1) v = fmaxf(v, 0.f);
                dp[i * 4 + r] = fmaf(v, dv, dp[i * 4 + r]);
                if (row >= Mstore) continue;
                if (flags & 2) outb[row * ldc + col] = __float2bfloat16(v);
                else           outf[row * ldc + col] = v;
            }
        }
    }

    if (dotout) {
#pragma unroll
        for (int t = 0; t < 16; t++) {
            float s = dp[t];
            s += __shfl_xor(s, 1); s += __shfl_xor(s, 2);
            s += __shfl_xor(s, 4); s += __shfl_xor(s, 8);
            if (l16 == 0) {
                long row = bm + wr + (t >> 2) * 16 + quad * 4 + (t & 3);
                if (row < Mstore) atomicAdd(&dotout[row], s);
            }
        }
    }
}

// ---------------- casts ----------------
__global__ void cast_x(const float* __restrict__ x, __hip_bfloat16* __restrict__ xb)
{
    int row = blockIdx.x;
    int col = threadIdx.x;           // 320 threads
    float v = (row < NN && col < 300) ? x[(size_t)row * 300 + col] : 0.f;
    xb[(size_t)row * 320 + col] = __float2bfloat16(v);
}

__global__ void cast_wT(const float* __restrict__ w, __hip_bfloat16* __restrict__ wt,
                        int K, int N, int Kp, int Np)
{
    int idx = blockIdx.x * 256 + threadIdx.x;
    if (idx >= Np * Kp) return;
    int n = idx / Kp, k = idx % Kp;
    float v = (n < N && k < K) ? w[(size_t)k * N + n] : 0.f;
    wt[idx] = __float2bfloat16(v);
}

// ---------------- CSR build ----------------
__global__ void count_edges(const int* __restrict__ ei, int* __restrict__ counts)
{
    int e = blockIdx.x * blockDim.x + threadIdx.x;
    if (e >= ETOT) return;
    int d = (e < NE) ? ei[NE + e] : (e - NE);
    atomicAdd(&counts[d], 1);
}

__global__ __launch_bounds__(256)
void scan_partial(const int* __restrict__ counts, int* __restrict__ blk)
{
    __shared__ int sh[256];
    const int tid = threadIdx.x;
    const int base = blockIdx.x * SCHUNK + tid * 2;
    int c0 = (base < NN)     ? counts[base]     : 0;
    int c1 = (base + 1 < NN) ? counts[base + 1] : 0;
    sh[tid] = c0 + c1;
    __syncthreads();
    for (int off = 128; off; off >>= 1) {
        if (tid < off) sh[tid] += sh[tid + off];
        __syncthreads();
    }
    if (tid == 0) blk[blockIdx.x] = sh[0];
}

__global__ __launch_bounds__(256)
void scan_blocks(int* __restrict__ blk)
{
    __shared__ int sh[256];
    const int tid = threadIdx.x;
    int v = (tid < NBLK) ? blk[tid] : 0;
    sh[tid] = v;
    __syncthreads();
    for (int off = 1; off < 256; off <<= 1) {
        int u = (tid >= off) ? sh[tid - off] : 0;
        __syncthreads();
        sh[tid] += u;
        __syncthreads();
    }
    if (tid < NBLK) blk[tid] = sh[tid] - v;   // exclusive
}

__global__ __launch_bounds__(256)
void scan_fill(const int* __restrict__ counts, const int* __restrict__ blk,
               int* __restrict__ row_ptr, int* __restrict__ cursor)
{
    __shared__ int sh[256];
    const int tid = threadIdx.x;
    const int i0 = blockIdx.x * SCHUNK + tid * 2;
    int c0 = (i0 < NN)     ? counts[i0]     : 0;
    int c1 = (i0 + 1 < NN) ? counts[i0 + 1] : 0;
    int s = c0 + c1;
    sh[tid] = s;
    __syncthreads();
    for (int off = 1; off < 256; off <<= 1) {
        int u = (tid >= off) ? sh[tid - off] : 0;
        __syncthreads();
        sh[tid] += u;
        __syncthreads();
    }
    int pre = sh[tid] - s + blk[blockIdx.x];
    if (i0 < NN)     { row_ptr[i0] = pre;          cursor[i0] = pre; }
    if (i0 + 1 < NN) { row_ptr[i0 + 1] = pre + c0; cursor[i0 + 1] = pre + c0; }
    if (blockIdx.x == 0 && tid == 0) row_ptr[NN] = ETOT;
}

__global__ void fill_edges(const int* __restrict__ ei, int* __restrict__ cursor,
                           int* __restrict__ csr_src)
{
    int e = blockIdx.x * blockDim.x + threadIdx.x;
    if (e >= ETOT) return;
    int s, d;
    if (e < NE) { s = ei[e]; d = ei[NE + e]; }
    else        { s = e - NE; d = s; }
    int pos = atomicAdd(&cursor[d], 1);
    csr_src[pos] = s;
}

// ---------------- small matvec helper (weights only) ----------------
__global__ void wv_kernel(const float* __restrict__ w, const float* __restrict__ a,
                          float* __restrict__ v, int Cin, int Cout)
{
    int i = blockIdx.x * blockDim.x + threadIdx.x;
    if (i >= Cin) return;
    float s = 0.f;
    for (int j = 0; j < Cout; j++) s = fmaf(w[(size_t)i * Cout + j], a[j], s);
    v[i] = s;
}

// ---------------- GAT attention + aggregation: one wave per node -----------
// CPL channels per lane (4 -> C=256, 2 -> C=128). No LDS; weights broadcast
// via shuffles; online-softmax rescale for deg > 64.
// Optional fused dot: dotout[n] = dot(out_row, dotv)  (next layer's a_d).
template<int CPL>
__global__ __launch_bounds__(256)
void gat_agg_wave(const __hip_bfloat16* __restrict__ hsrc,
                  const float* __restrict__ a_s,
                  const float* __restrict__ a_d,
                  const int* __restrict__ row_ptr,
                  const int* __restrict__ csr_src,
                  const float* __restrict__ bias,
                  __hip_bfloat16* __restrict__ outh,
                  const float* __restrict__ dotv,
                  float* __restrict__ dotout)
{
    const int lane = threadIdx.x & 63;
    const int n = blockIdx.x * 4 + (threadIdx.x >> 6);
    if (n >= NN) return;
    const int C = CPL * 64;
    const int start = row_ptr[n];
    const int deg = row_ptr[n + 1] - start;
    const float a_dn = a_d[n];
    const ushort* hp = (const ushort*)hsrc;

    float M = -3e30f, S = 0.f;
    float acc[CPL];
#pragma unroll
    for (int k = 0; k < CPL; k++) acc[k] = 0.f;

    for (int c0 = 0; c0 < deg; c0 += 64) {
        const int cnt = min(64, deg - c0);
        int sj = 0;
        float e = -3e30f;
        if (lane < cnt) {
            sj = csr_src[start + c0 + lane];
            float t = a_s[sj] + a_dn;
            e = (t >= 0.f) ? t : 0.2f * t;
        }
        float cm = e;
#pragma unroll
        for (int off = 32; off; off >>= 1) cm = fmaxf(cm, __shfl_xor(cm, off));
        float newM = fmaxf(M, cm);
        float w = (lane < cnt) ? __expf(e - newM) : 0.f;
        float cs = w;
#pragma unroll
        for (int off = 32; off; off >>= 1) cs += __shfl_xor(cs, off);
        float scale = __expf(M - newM);     // 0 on first chunk, 1 if M unchanged
        S = S * scale + cs;
#pragma unroll
        for (int k = 0; k < CPL; k++) acc[k] *= scale;
        M = newM;

        for (int j = 0; j < cnt; j++) {
            float wj = __shfl(w, j);
            int s = __shfl(sj, j);
            const ushort* rp = hp + (size_t)s * C + lane * CPL;
            if (CPL == 4) {
                uint2 u = *(const uint2*)rp;
                acc[0] = fmaf(wj, __uint_as_float(u.x << 16), acc[0]);
                acc[1] = fmaf(wj, __uint_as_float(u.x & 0xffff0000u), acc[1]);
                acc[2] = fmaf(wj, __uint_as_float(u.y << 16), acc[2]);
                acc[3] = fmaf(wj, __uint_as_float(u.y & 0xffff0000u), acc[3]);
            } else {
                uint u = *(const uint*)rp;
                acc[0] = fmaf(wj, __uint_as_float(u << 16), acc[0]);
                acc[1] = fmaf(wj, __uint_as_float(u & 0xffff0000u), acc[1]);
            }
        }
    }

    float inv = 1.f / (S + 1e-16f);
    float o[CPL];
    float dp = 0.f;
#pragma unroll
    for (int k = 0; k < CPL; k++) {
        o[k] = fmaxf(acc[k] * inv + bias[lane * CPL + k], 0.f);
        if (dotout) dp = fmaf(o[k], dotv[lane * CPL + k], dp);
    }
    if (CPL == 4) {
        ushort4 pk;
        pk.x = *(ushort*)&(__hip_bfloat16_raw&)(__hip_bfloat16&)(*(__hip_bfloat16[]){__float2bfloat16(o[0])});
        // (packing done simply below instead)
        __hip_bfloat16 b0 = __float2bfloat16(o[0]), b1 = __float2bfloat16(o[1]);
        __hip_bfloat16 b2 = __float2bfloat16(o[2]), b3 = __float2bfloat16(o[3]);
        ushort4 v;
        v.x = *(ushort*)&b0; v.y = *(ushort*)&b1; v.z = *(ushort*)&b2; v.w = *(ushort*)&b3;
        *(ushort4*)((ushort*)outh + (size_t)n * C + lane * 4) = v;
    } else {
        __hip_bfloat16 b0 = __float2bfloat16(o[0]), b1 = __float2bfloat16(o[1]);
        ushort2 v;
        v.x = *(ushort*)&b0; v.y = *(ushort*)&b1;
        *(ushort2*)((ushort*)outh + (size_t)n * C + lane * 2) = v;
    }
    if (dotout) {
#pragma unroll
        for (int off = 32; off; off >>= 1) dp += __shfl_xor(dp, off);
        if (lane == 0) dotout[n] = dp;
    }
}

// ---------------- BatchNorm stats + finalize ----------------
__global__ __launch_bounds__(256)
void bn_stats(const float* __restrict__ h, float* __restrict__ stats)
{
    int col = threadIdx.x & 63;
    int rg = threadIdx.x >> 6;
    int r0 = blockIdx.x * 256;
    int r1 = min(r0 + 256, NN);
    float s = 0.f, s2 = 0.f;
    for (int r = r0 + rg; r < r1; r += 4) {
        float v = h[(size_t)r * 64 + col];
        s += v; s2 += v * v;
    }
    __shared__ float sh[2][4][64];
    sh[0][rg][col] = s; sh[1][rg][col] = s2;
    __syncthreads();
    if (rg == 0) {
        s  = sh[0][0][col] + sh[0][1][col] + sh[0][2][col] + sh[0][3][col];
        s2 = sh[1][0][col] + sh[1][1][col] + sh[1][2][col] + sh[1][3][col];
        atomicAdd(&stats[col], s);
        atomicAdd(&stats[64 + col], s2);
    }
}

__global__ void bn_finalize(const float* __restrict__ stats,
                            const float* __restrict__ g, const float* __restrict__ b,
                            float* __restrict__ ss)
{
    int c = threadIdx.x;
    float mu = stats[c] / (float)NN;
    float var = stats[64 + c] / (float)NN - mu * mu;
    float rs = rsqrtf(var + 1e-5f);
    float sc = rs * g[c];
    ss[c] = sc;
    ss[64 + c] = b[c] - mu * sc;
}

__global__ __launch_bounds__(256)
void final_head(const float* __restrict__ h3, const float* __restrict__ ss,
                const float* __restrict__ fc2_w, const float* __restrict__ fc2_b,
                float* __restrict__ out)
{
    int lane = threadIdx.x & 63;
    int n = blockIdx.x * 4 + (threadIdx.x >> 6);
    if (n >= NN) return;
    float y = h3[(size_t)n * 64 + lane];
    y = fmaxf(y * ss[lane] + ss[64 + lane], 0.f);
    float z[4];
#pragma unroll
    for (int o = 0; o < 4; o++) {
        float p = y * fc2_w[lane * 4 + o];
#pragma unroll
        for (int off = 32; off; off >>= 1) p += __shfl_xor(p, off);
        z[o] = p + fc2_b[o];
    }
    float mx = fmaxf(fmaxf(z[0], z[1]), fmaxf(z[2], z[3]));
    float lse = mx + logf(expf(z[0] - mx) + expf(z[1] - mx) +
                          expf(z[2] - mx) + expf(z[3] - mx));
    if (lane < 4) out[(size_t)n * 4 + lane] = z[lane] - lse;
}

// ---------------- launch ----------------
extern "C" void kernel_launch(void* const* d_in, const int* in_sizes, int n_in,
                              void* d_out, int out_size, void* d_ws, size_t ws_size,
                              hipStream_t stream)
{
    const float* x      = (const float*)d_in[0];
    const int*   ei     = (const int*)d_in[1];
    const float* lin_w  = (const float*)d_in[2];
    const float* lin_b  = (const float*)d_in[3];
    const float* w1_src = (const float*)d_in[4];
    const float* w1_dst = (const float*)d_in[5];
    const float* a1_src = (const float*)d_in[6];
    const float* a1_dst = (const float*)d_in[7];
    const float* b1     = (const float*)d_in[8];
    const float* w2_src = (const float*)d_in[9];
    const float* w2_dst = (const float*)d_in[10];
    const float* a2_src = (const float*)d_in[11];
    const float* a2_dst = (const float*)d_in[12];
    const float* b2     = (const float*)d_in[13];
    const float* fc1_w  = (const float*)d_in[14];
    const float* fc1_b  = (const float*)d_in[15];
    const float* bn_g   = (const float*)d_in[16];
    const float* bn_b   = (const float*)d_in[17];
    const float* fc2_w  = (const float*)d_in[18];
    const float* fc2_b  = (const float*)d_in[19];
    float* out = (float*)d_out;

    // -------- workspace layout (region reuse) --------
    char* p = (char*)d_ws;
    auto alloc = [&](size_t bytes) { char* r = p; p += (bytes + 255) & ~(size_t)255; return r; };
    char* R1 = alloc((size_t)MP * 320 * 2);   // x_bf  -> hsrc1
    char* R2 = alloc((size_t)MP * 256 * 2);   // h0    -> hsrc2 | h2
    char* R3 = alloc((size_t)MP * 256 * 2);   // h1    -> h3(f32)
    __hip_bfloat16* wlinT = (__hip_bfloat16*)alloc(256 * 320 * 2);
    __hip_bfloat16* w1T   = (__hip_bfloat16*)alloc(256 * 256 * 2);
    __hip_bfloat16* w2T   = (__hip_bfloat16*)alloc(128 * 256 * 2);
    __hip_bfloat16* fc1T  = (__hip_bfloat16*)alloc(128 * 128 * 2);
    float* aS1   = (float*)alloc((size_t)NN * 4);
    float* aD1   = (float*)alloc((size_t)NN * 4);
    float* aS2   = (float*)alloc((size_t)NN * 4);
    float* aD2   = (float*)alloc((size_t)NN * 4);
    float* vvec1 = (float*)alloc(256 * 4);
    float* vvec2 = (float*)alloc(256 * 4);
    float* ss    = (float*)alloc(128 * 4);
    float* stats = (float*)alloc(128 * 4);
    int* row_ptr = (int*)alloc((size_t)(NN + 1) * 4);
    int* cursor  = (int*)alloc((size_t)(NN + 1) * 4);
    int* counts  = (int*)alloc((size_t)NN * 4);
    int* blk     = (int*)alloc(256 * 4);
    int* csr_src = (int*)alloc((size_t)ETOT * 4);

    __hip_bfloat16* x_bf  = (__hip_bfloat16*)R1;
    __hip_bfloat16* hsrc1 = (__hip_bfloat16*)R1;
    __hip_bfloat16* h0    = (__hip_bfloat16*)R2;
    __hip_bfloat16* hsrc2 = (__hip_bfloat16*)R2;
    __hip_bfloat16* h2    = (__hip_bfloat16*)(R2 + (size_t)MP * 128 * 2);
    __hip_bfloat16* h1    = (__hip_bfloat16*)R3;
    float*          h3    = (float*)R3;

    const int eb = (ETOT + 255) / 256;
    const int MB = MP / 128;   // 782

    // zero the atomic dot outputs (one upfront memset covers aS1..aD2)
    hipMemsetAsync(aS1, 0, sizeof(float) * NN * 4, stream);

    // CSR build (parallel 3-phase scan; reused by both GAT layers)
    hipMemsetAsync(counts, 0, sizeof(int) * NN, stream);
    count_edges<<<eb, 256, 0, stream>>>(ei, counts);
    scan_partial<<<NBLK, 256, 0, stream>>>(counts, blk);
    scan_blocks<<<1, 256, 0, stream>>>(blk);
    scan_fill<<<NBLK, 256, 0, stream>>>(counts, blk, row_ptr, cursor);
    fill_edges<<<eb, 256, 0, stream>>>(ei, cursor, csr_src);

    // casts + attention weight matvecs
    cast_x<<<MP, 320, 0, stream>>>(x, x_bf);
    cast_wT<<<(256 * 320 + 255) / 256, 256, 0, stream>>>(lin_w, wlinT, 300, 256, 320, 256);
    cast_wT<<<(256 * 256 + 255) / 256, 256, 0, stream>>>(w1_src, w1T, 256, 256, 256, 256);
    cast_wT<<<(128 * 256 + 255) / 256, 256, 0, stream>>>(w2_src, w2T, 256, 128, 256, 128);
    cast_wT<<<(128 * 128 + 255) / 256, 256, 0, stream>>>(fc1_w, fc1T, 128, 64, 128, 128);
    wv_kernel<<<4, 64, 0, stream>>>(w1_dst, a1_dst, vvec1, 256, 256);
    wv_kernel<<<4, 64, 0, stream>>>(w2_dst, a2_dst, vvec2, 256, 128);

    // h0 = relu(x @ lin_w + lin_b)   [bf16 out]; fused: aD1 = h0 @ vvec1
    mfma_gemm<<<dim3(MB, 2), 256, 0, stream>>>(x_bf, wlinT, lin_b, h0,
                                               vvec1, aD1, 320, 256, NN, 256, 3);

    // ---- GAT layer 1 (256 -> 256) ----
    // hsrc1 = h0 @ w1_src; fused: aS1 = hsrc1 @ a1_src
    mfma_gemm<<<dim3(MB, 2), 256, 0, stream>>>(h0, w1T, nullptr, hsrc1,
                                               a1_src, aS1, 256, 256, NN, 256, 2);
    // h1 = relu(aggregate + b1); fused: aD2 = h1 @ vvec2
    gat_agg_wave<4><<<(NN + 3) / 4, 256, 0, stream>>>(hsrc1, aS1, aD1, row_ptr,
                                                      csr_src, b1, h1, vvec2, aD2);

    // ---- GAT layer 2 (256 -> 128) ----
    // hsrc2 = h1 @ w2_src; fused: aS2 = hsrc2 @ a2_src
    mfma_gemm<<<dim3(MB, 1), 256, 0, stream>>>(h1, w2T, nullptr, hsrc2,
                                               a2_src, aS2, 256, 128, NN, 128, 2);
    gat_agg_wave<2><<<(NN + 3) / 4, 256, 0, stream>>>(hsrc2, aS2, aD2, row_ptr,
                                                      csr_src, b2, h2, nullptr, nullptr);

    // ---- fc1 + BN + relu + fc2 + log_softmax ----
    mfma_gemm<<<dim3(MB, 1), 256, 0, stream>>>(h2, fc1T, fc1_b, h3,
                                               nullptr, nullptr, 128, 64, NN, 64, 0);
    hipMemsetAsync(stats, 0, sizeof(float) * 128, stream);
    bn_stats<<<(NN + 255) / 256, 256, 0, stream>>>(h3, stats);
    bn_finalize<<<1, 64, 0, stream>>>(stats, bn_g, bn_b, ss);
    final_head<<<(NN + 3) / 4, 256, 0, stream>>>(h3, ss, fc2_w, fc2_b, out);
}

// Round 5
// 724.983 us; speedup vs baseline: 2.2416x; 1.1279x over previous
//
#include <hip/hip_runtime.h>
#include <hip/hip_bf16.h>
#include <cmath>

#define NN 100000
#define NE 800000
#define ETOT (NE + NN)
#define MP 100096            // 782 * 128, padded row count

#define SCHUNK 512
#define NBLK ((NN + SCHUNK - 1) / SCHUNK)   // 196

typedef __attribute__((ext_vector_type(8))) short bf16x8;
typedef __attribute__((ext_vector_type(4))) float f32x4;

__device__ inline void gl_lds16(const void* g, void* l) {
    __builtin_amdgcn_global_load_lds(
        (const __attribute__((address_space(1))) void*)g,
        (__attribute__((address_space(3))) void*)l, 16, 0, 0);
}

__device__ inline ushort f2bf(float f) {
    __hip_bfloat16 b = __float2bfloat16(f);
    return *(ushort*)&b;
}

// ---------------- MFMA GEMM: C[M,N] = A[M,Kp] @ Bt[N,Kp]^T ------------------
// 128x128 tile, 4 waves, each wave 64x64 = 4x4 MFMA tiles of 16x16x32 bf16.
// flags: 1 = relu, 2 = bf16 output (else fp32)
// Optional fused row-dot: dotout[row] += sum_col v[row,col]*dotv[col]
__global__ __launch_bounds__(256)
void mfma_gemm(const __hip_bfloat16* __restrict__ Abf,
               const __hip_bfloat16* __restrict__ Btbf,
               const float* __restrict__ bias, void* __restrict__ out,
               const float* __restrict__ dotv, float* __restrict__ dotout,
               int Kp, int ldc, int Mstore, int Nstore, int flags)
{
    __shared__ __align__(16) short As[128 * 32];
    __shared__ __align__(16) short Bs[128 * 32];
    const short* A  = (const short*)Abf;
    const short* Bt = (const short*)Btbf;

    const int tid  = threadIdx.x;
    const int lane = tid & 63;
    const int wv   = tid >> 6;
    const int wr   = (wv >> 1) * 64;
    const int wc   = (wv & 1) * 64;
    const int quad = lane >> 4;
    const int l16  = lane & 15;
    const long bm = (long)blockIdx.x * 128;
    const long bn = (long)blockIdx.y * 128;

    const int r0 = tid >> 2;
    const int c0 = (tid & 3) ^ ((r0 >> 1) & 3);
    const int r1 = r0 + 64;
    const int c1 = (tid & 3) ^ ((r1 >> 1) & 3);
    const short* a_g0 = A + (bm + r0) * (long)Kp + c0 * 8;
    const short* a_g1 = A + (bm + r1) * (long)Kp + c1 * 8;
    const short* b_g0 = Bt + (bn + r0) * (long)Kp + c0 * 8;
    const short* b_g1 = Bt + (bn + r1) * (long)Kp + c1 * 8;
    short* a_l0 = &As[tid * 8];
    short* a_l1 = &As[(tid + 256) * 8];
    short* b_l0 = &Bs[tid * 8];
    short* b_l1 = &Bs[(tid + 256) * 8];

    f32x4 acc[4][4] = {};
    const int xr = (quad ^ ((l16 >> 1) & 3)) * 8;

    for (int k0 = 0; k0 < Kp; k0 += 32) {
        gl_lds16(a_g0 + k0, a_l0);
        gl_lds16(a_g1 + k0, a_l1);
        gl_lds16(b_g0 + k0, b_l0);
        gl_lds16(b_g1 + k0, b_l1);
        __syncthreads();

        bf16x8 af[4], bf[4];
#pragma unroll
        for (int i = 0; i < 4; i++)
            af[i] = *(const bf16x8*)&As[(wr + i * 16 + l16) * 32 + xr];
#pragma unroll
        for (int j = 0; j < 4; j++)
            bf[j] = *(const bf16x8*)&Bs[(wc + j * 16 + l16) * 32 + xr];
#pragma unroll
        for (int i = 0; i < 4; i++)
#pragma unroll
            for (int j = 0; j < 4; j++)
                acc[i][j] = __builtin_amdgcn_mfma_f32_16x16x32_bf16(
                    af[i], bf[j], acc[i][j], 0, 0, 0);
        __syncthreads();
    }

    __hip_bfloat16* outb = (__hip_bfloat16*)out;
    float* outf = (float*)out;
    float dp[16];
#pragma unroll
    for (int t = 0; t < 16; t++) dp[t] = 0.f;

#pragma unroll
    for (int i = 0; i < 4; i++) {
        long row_base = bm + wr + i * 16 + quad * 4;
#pragma unroll
        for (int j = 0; j < 4; j++) {
            long col = bn + wc + j * 16 + l16;
            if (col >= Nstore) continue;
            float bv = bias ? bias[col] : 0.f;
            float dv = dotout ? dotv[col] : 0.f;
#pragma unroll
            for (int r = 0; r < 4; r++) {
                long row = row_base + r;
                float v = acc[i][j][r] + bv;
                if (flags & 1) v = fmaxf(v, 0.f);
                dp[i * 4 + r] = fmaf(v, dv, dp[i * 4 + r]);
                if (row >= Mstore) continue;
                if (flags & 2) outb[row * ldc + col] = __float2bfloat16(v);
                else           outf[row * ldc + col] = v;
            }
        }
    }

    if (dotout) {
#pragma unroll
        for (int t = 0; t < 16; t++) {
            float s = dp[t];
            s += __shfl_xor(s, 1); s += __shfl_xor(s, 2);
            s += __shfl_xor(s, 4); s += __shfl_xor(s, 8);
            if (l16 == 0) {
                long row = bm + wr + (t >> 2) * 16 + quad * 4 + (t & 3);
                if (row < Mstore) atomicAdd(&dotout[row], s);
            }
        }
    }
}

// ---------------- casts ----------------
__global__ void cast_x(const float* __restrict__ x, __hip_bfloat16* __restrict__ xb)
{
    int row = blockIdx.x;
    int col = threadIdx.x;           // 320 threads
    float v = (row < NN && col < 300) ? x[(size_t)row * 300 + col] : 0.f;
    xb[(size_t)row * 320 + col] = __float2bfloat16(v);
}

__global__ void cast_wT(const float* __restrict__ w, __hip_bfloat16* __restrict__ wt,
                        int K, int N, int Kp, int Np)
{
    int idx = blockIdx.x * 256 + threadIdx.x;
    if (idx >= Np * Kp) return;
    int n = idx / Kp, k = idx % Kp;
    float v = (n < N && k < K) ? w[(size_t)k * N + n] : 0.f;
    wt[idx] = __float2bfloat16(v);
}

// ---------------- CSR build ----------------
__global__ void count_edges(const int* __restrict__ ei, int* __restrict__ counts)
{
    int e = blockIdx.x * blockDim.x + threadIdx.x;
    if (e >= ETOT) return;
    int d = (e < NE) ? ei[NE + e] : (e - NE);
    atomicAdd(&counts[d], 1);
}

__global__ __launch_bounds__(256)
void scan_partial(const int* __restrict__ counts, int* __restrict__ blk)
{
    __shared__ int sh[256];
    const int tid = threadIdx.x;
    const int base = blockIdx.x * SCHUNK + tid * 2;
    int c0 = (base < NN)     ? counts[base]     : 0;
    int c1 = (base + 1 < NN) ? counts[base + 1] : 0;
    sh[tid] = c0 + c1;
    __syncthreads();
    for (int off = 128; off; off >>= 1) {
        if (tid < off) sh[tid] += sh[tid + off];
        __syncthreads();
    }
    if (tid == 0) blk[blockIdx.x] = sh[0];
}

__global__ __launch_bounds__(256)
void scan_blocks(int* __restrict__ blk)
{
    __shared__ int sh[256];
    const int tid = threadIdx.x;
    int v = (tid < NBLK) ? blk[tid] : 0;
    sh[tid] = v;
    __syncthreads();
    for (int off = 1; off < 256; off <<= 1) {
        int u = (tid >= off) ? sh[tid - off] : 0;
        __syncthreads();
        sh[tid] += u;
        __syncthreads();
    }
    if (tid < NBLK) blk[tid] = sh[tid] - v;   // exclusive
}

__global__ __launch_bounds__(256)
void scan_fill(const int* __restrict__ counts, const int* __restrict__ blk,
               int* __restrict__ row_ptr, int* __restrict__ cursor)
{
    __shared__ int sh[256];
    const int tid = threadIdx.x;
    const int i0 = blockIdx.x * SCHUNK + tid * 2;
    int c0 = (i0 < NN)     ? counts[i0]     : 0;
    int c1 = (i0 + 1 < NN) ? counts[i0 + 1] : 0;
    int s = c0 + c1;
    sh[tid] = s;
    __syncthreads();
    for (int off = 1; off < 256; off <<= 1) {
        int u = (tid >= off) ? sh[tid - off] : 0;
        __syncthreads();
        sh[tid] += u;
        __syncthreads();
    }
    int pre = sh[tid] - s + blk[blockIdx.x];
    if (i0 < NN)     { row_ptr[i0] = pre;          cursor[i0] = pre; }
    if (i0 + 1 < NN) { row_ptr[i0 + 1] = pre + c0; cursor[i0 + 1] = pre + c0; }
    if (blockIdx.x == 0 && tid == 0) row_ptr[NN] = ETOT;
}

__global__ void fill_edges(const int* __restrict__ ei, int* __restrict__ cursor,
                           int* __restrict__ csr_src)
{
    int e = blockIdx.x * blockDim.x + threadIdx.x;
    if (e >= ETOT) return;
    int s, d;
    if (e < NE) { s = ei[e]; d = ei[NE + e]; }
    else        { s = e - NE; d = s; }
    int pos = atomicAdd(&cursor[d], 1);
    csr_src[pos] = s;
}

// ---------------- small matvec helper (weights only) ----------------
__global__ void wv_kernel(const float* __restrict__ w, const float* __restrict__ a,
                          float* __restrict__ v, int Cin, int Cout)
{
    int i = blockIdx.x * blockDim.x + threadIdx.x;
    if (i >= Cin) return;
    float s = 0.f;
    for (int j = 0; j < Cout; j++) s = fmaf(w[(size_t)i * Cout + j], a[j], s);
    v[i] = s;
}

// ---------------- GAT attention + aggregation ------------------------------
// LPN lanes per node, 4 channels per lane (C = LPN*4). LPN=64 -> C=256,
// LPN=32 -> C=128 (2 nodes per wave). (w,src) pairs staged in per-wave LDS,
// then edges processed in groups of 4: 2x ds_read_b128 broadcast + 4
// independent dwordx2 gathers in flight (MLP). Online softmax for deg > LPN.
// Optional fused dot: dotout[n] = dot(out_row, dotv).
template<int LPN>
__global__ __launch_bounds__(256)
void gat_agg_wave(const __hip_bfloat16* __restrict__ hsrc,
                  const float* __restrict__ a_s,
                  const float* __restrict__ a_d,
                  const int* __restrict__ row_ptr,
                  const int* __restrict__ csr_src,
                  const float* __restrict__ bias,
                  __hip_bfloat16* __restrict__ outh,
                  const float* __restrict__ dotv,
                  float* __restrict__ dotout)
{
    const int C = LPN * 4;
    const int NPB = 256 / LPN;               // nodes per block
    __shared__ __align__(16) float2 ws_sh[NPB][LPN];

    const int tid  = threadIdx.x;
    const int slot = tid / LPN;
    const int sub  = tid % LPN;
    const int n = blockIdx.x * NPB + slot;
    if (n >= NN) return;

    const int start = row_ptr[n];
    const int deg = row_ptr[n + 1] - start;
    const float a_dn = a_d[n];
    const ushort* hp = (const ushort*)hsrc;

    float M = -3e30f, S = 0.f;
    float acc0 = 0.f, acc1 = 0.f, acc2 = 0.f, acc3 = 0.f;

    for (int c0 = 0; c0 < deg; c0 += LPN) {
        const int cnt = min(LPN, deg - c0);
        int sj = 0;
        float e = -3e30f;
        if (sub < cnt) {
            sj = csr_src[start + c0 + sub];
            float t = a_s[sj] + a_dn;
            e = (t >= 0.f) ? t : 0.2f * t;
        }
        float cm = e;
#pragma unroll
        for (int off = LPN / 2; off; off >>= 1) cm = fmaxf(cm, __shfl_xor(cm, off));
        float newM = fmaxf(M, cm);
        float w = (sub < cnt) ? __expf(e - newM) : 0.f;
        float cs = w;
#pragma unroll
        for (int off = LPN / 2; off; off >>= 1) cs += __shfl_xor(cs, off);
        float scale = __expf(M - newM);      // 0 on first chunk, 1 if M unchanged
        S = S * scale + cs;
        acc0 *= scale; acc1 *= scale; acc2 *= scale; acc3 *= scale;
        M = newM;

        // stage (w, src) pairs; pad lanes hold w=0, s=0 (row 0 stays cache-hot)
        ws_sh[slot][sub] = make_float2(w, __int_as_float(sj));
        const int cnt4 = (cnt + 3) & ~3;
        const ushort* hpl = hp + sub * 4;
        for (int j = 0; j < cnt4; j += 4) {
            float4 p0 = *(const float4*)&ws_sh[slot][j];
            float4 p1 = *(const float4*)&ws_sh[slot][j + 2];
            const ushort* r0 = hpl + (size_t)__float_as_int(p0.y) * C;
            const ushort* r1 = hpl + (size_t)__float_as_int(p0.w) * C;
            const ushort* r2 = hpl + (size_t)__float_as_int(p1.y) * C;
            const ushort* r3 = hpl + (size_t)__float_as_int(p1.w) * C;
            uint2 u0 = *(const uint2*)r0;
            uint2 u1 = *(const uint2*)r1;
            uint2 u2 = *(const uint2*)r2;
            uint2 u3 = *(const uint2*)r3;
            acc0 = fmaf(p0.x, __uint_as_float(u0.x << 16), acc0);
            acc1 = fmaf(p0.x, __uint_as_float(u0.x & 0xffff0000u), acc1);
            acc2 = fmaf(p0.x, __uint_as_float(u0.y << 16), acc2);
            acc3 = fmaf(p0.x, __uint_as_float(u0.y & 0xffff0000u), acc3);
            acc0 = fmaf(p0.z, __uint_as_float(u1.x << 16), acc0);
            acc1 = fmaf(p0.z, __uint_as_float(u1.x & 0xffff0000u), acc1);
            acc2 = fmaf(p0.z, __uint_as_float(u1.y << 16), acc2);
            acc3 = fmaf(p0.z, __uint_as_float(u1.y & 0xffff0000u), acc3);
            acc0 = fmaf(p1.x, __uint_as_float(u2.x << 16), acc0);
            acc1 = fmaf(p1.x, __uint_as_float(u2.x & 0xffff0000u), acc1);
            acc2 = fmaf(p1.x, __uint_as_float(u2.y << 16), acc2);
            acc3 = fmaf(p1.x, __uint_as_float(u2.y & 0xffff0000u), acc3);
            acc0 = fmaf(p1.z, __uint_as_float(u3.x << 16), acc0);
            acc1 = fmaf(p1.z, __uint_as_float(u3.x & 0xffff0000u), acc1);
            acc2 = fmaf(p1.z, __uint_as_float(u3.y << 16), acc2);
            acc3 = fmaf(p1.z, __uint_as_float(u3.y & 0xffff0000u), acc3);
        }
    }

    float inv = 1.f / (S + 1e-16f);
    float o0 = fmaxf(acc0 * inv + bias[sub * 4 + 0], 0.f);
    float o1 = fmaxf(acc1 * inv + bias[sub * 4 + 1], 0.f);
    float o2 = fmaxf(acc2 * inv + bias[sub * 4 + 2], 0.f);
    float o3 = fmaxf(acc3 * inv + bias[sub * 4 + 3], 0.f);

    ushort4 v;
    v.x = f2bf(o0); v.y = f2bf(o1); v.z = f2bf(o2); v.w = f2bf(o3);
    *(ushort4*)((ushort*)outh + (size_t)n * C + sub * 4) = v;

    if (dotout) {
        float dp = o0 * dotv[sub * 4 + 0] + o1 * dotv[sub * 4 + 1]
                 + o2 * dotv[sub * 4 + 2] + o3 * dotv[sub * 4 + 3];
#pragma unroll
        for (int off = LPN / 2; off; off >>= 1) dp += __shfl_xor(dp, off);
        if (sub == 0) dotout[n] = dp;
    }
}

// ---------------- BatchNorm stats + finalize ----------------
__global__ __launch_bounds__(256)
void bn_stats(const float* __restrict__ h, float* __restrict__ stats)
{
    int col = threadIdx.x & 63;
    int rg = threadIdx.x >> 6;
    int r0 = blockIdx.x * 256;
    int r1 = min(r0 + 256, NN);
    float s = 0.f, s2 = 0.f;
    for (int r = r0 + rg; r < r1; r += 4) {
        float v = h[(size_t)r * 64 + col];
        s += v; s2 += v * v;
    }
    __shared__ float sh[2][4][64];
    sh[0][rg][col] = s; sh[1][rg][col] = s2;
    __syncthreads();
    if (rg == 0) {
        s  = sh[0][0][col] + sh[0][1][col] + sh[0][2][col] + sh[0][3][col];
        s2 = sh[1][0][col] + sh[1][1][col] + sh[1][2][col] + sh[1][3][col];
        atomicAdd(&stats[col], s);
        atomicAdd(&stats[64 + col], s2);
    }
}

__global__ void bn_finalize(const float* __restrict__ stats,
                            const float* __restrict__ g, const float* __restrict__ b,
                            float* __restrict__ ss)
{
    int c = threadIdx.x;
    float mu = stats[c] / (float)NN;
    float var = stats[64 + c] / (float)NN - mu * mu;
    float rs = rsqrtf(var + 1e-5f);
    float sc = rs * g[c];
    ss[c] = sc;
    ss[64 + c] = b[c] - mu * sc;
}

__global__ __launch_bounds__(256)
void final_head(const float* __restrict__ h3, const float* __restrict__ ss,
                const float* __restrict__ fc2_w, const float* __restrict__ fc2_b,
                float* __restrict__ out)
{
    int lane = threadIdx.x & 63;
    int n = blockIdx.x * 4 + (threadIdx.x >> 6);
    if (n >= NN) return;
    float y = h3[(size_t)n * 64 + lane];
    y = fmaxf(y * ss[lane] + ss[64 + lane], 0.f);
    float z[4];
#pragma unroll
    for (int o = 0; o < 4; o++) {
        float p = y * fc2_w[lane * 4 + o];
#pragma unroll
        for (int off = 32; off; off >>= 1) p += __shfl_xor(p, off);
        z[o] = p + fc2_b[o];
    }
    float mx = fmaxf(fmaxf(z[0], z[1]), fmaxf(z[2], z[3]));
    float lse = mx + logf(expf(z[0] - mx) + expf(z[1] - mx) +
                          expf(z[2] - mx) + expf(z[3] - mx));
    if (lane < 4) out[(size_t)n * 4 + lane] = z[lane] - lse;
}

// ---------------- launch ----------------
extern "C" void kernel_launch(void* const* d_in, const int* in_sizes, int n_in,
                              void* d_out, int out_size, void* d_ws, size_t ws_size,
                              hipStream_t stream)
{
    const float* x      = (const float*)d_in[0];
    const int*   ei     = (const int*)d_in[1];
    const float* lin_w  = (const float*)d_in[2];
    const float* lin_b  = (const float*)d_in[3];
    const float* w1_src = (const float*)d_in[4];
    const float* w1_dst = (const float*)d_in[5];
    const float* a1_src = (const float*)d_in[6];
    const float* a1_dst = (const float*)d_in[7];
    const float* b1     = (const float*)d_in[8];
    const float* w2_src = (const float*)d_in[9];
    const float* w2_dst = (const float*)d_in[10];
    const float* a2_src = (const float*)d_in[11];
    const float* a2_dst = (const float*)d_in[12];
    const float* b2     = (const float*)d_in[13];
    const float* fc1_w  = (const float*)d_in[14];
    const float* fc1_b  = (const float*)d_in[15];
    const float* bn_g   = (const float*)d_in[16];
    const float* bn_b   = (const float*)d_in[17];
    const float* fc2_w  = (const float*)d_in[18];
    const float* fc2_b  = (const float*)d_in[19];
    float* out = (float*)d_out;

    // -------- workspace layout (region reuse) --------
    char* p = (char*)d_ws;
    auto alloc = [&](size_t bytes) { char* r = p; p += (bytes + 255) & ~(size_t)255; return r; };
    char* R1 = alloc((size_t)MP * 320 * 2);   // x_bf  -> hsrc1
    char* R2 = alloc((size_t)MP * 256 * 2);   // h0    -> hsrc2 | h2
    char* R3 = alloc((size_t)MP * 256 * 2);   // h1    -> h3(f32)
    __hip_bfloat16* wlinT = (__hip_bfloat16*)alloc(256 * 320 * 2);
    __hip_bfloat16* w1T   = (__hip_bfloat16*)alloc(256 * 256 * 2);
    __hip_bfloat16* w2T   = (__hip_bfloat16*)alloc(128 * 256 * 2);
    __hip_bfloat16* fc1T  = (__hip_bfloat16*)alloc(128 * 128 * 2);
    float* avec  = (float*)alloc((size_t)NN * 4 * 4);   // aS1|aD1|aS2|aD2 contiguous
    float* aS1 = avec;
    float* aD1 = avec + NN;
    float* aS2 = avec + 2 * (size_t)NN;
    float* aD2 = avec + 3 * (size_t)NN;
    float* vvec1 = (float*)alloc(256 * 4);
    float* vvec2 = (float*)alloc(256 * 4);
    float* ss    = (float*)alloc(128 * 4);
    float* stats = (float*)alloc(128 * 4);
    int* row_ptr = (int*)alloc((size_t)(NN + 1) * 4);
    int* cursor  = (int*)alloc((size_t)(NN + 1) * 4);
    int* counts  = (int*)alloc((size_t)NN * 4);
    int* blk     = (int*)alloc(256 * 4);
    int* csr_src = (int*)alloc((size_t)ETOT * 4);

    __hip_bfloat16* x_bf  = (__hip_bfloat16*)R1;
    __hip_bfloat16* hsrc1 = (__hip_bfloat16*)R1;
    __hip_bfloat16* h0    = (__hip_bfloat16*)R2;
    __hip_bfloat16* hsrc2 = (__hip_bfloat16*)R2;
    __hip_bfloat16* h2    = (__hip_bfloat16*)(R2 + (size_t)MP * 128 * 2);
    __hip_bfloat16* h1    = (__hip_bfloat16*)R3;
    float*          h3    = (float*)R3;

    const int eb = (ETOT + 255) / 256;
    const int MB = MP / 128;   // 782

    // zero the atomic dot outputs (contiguous block, fully covered)
    hipMemsetAsync(avec, 0, sizeof(float) * NN * 4, stream);

    // CSR build (parallel 3-phase scan; reused by both GAT layers)
    hipMemsetAsync(counts, 0, sizeof(int) * NN, stream);
    count_edges<<<eb, 256, 0, stream>>>(ei, counts);
    scan_partial<<<NBLK, 256, 0, stream>>>(counts, blk);
    scan_blocks<<<1, 256, 0, stream>>>(blk);
    scan_fill<<<NBLK, 256, 0, stream>>>(counts, blk, row_ptr, cursor);
    fill_edges<<<eb, 256, 0, stream>>>(ei, cursor, csr_src);

    // casts + attention weight matvecs
    cast_x<<<MP, 320, 0, stream>>>(x, x_bf);
    cast_wT<<<(256 * 320 + 255) / 256, 256, 0, stream>>>(lin_w, wlinT, 300, 256, 320, 256);
    cast_wT<<<(256 * 256 + 255) / 256, 256, 0, stream>>>(w1_src, w1T, 256, 256, 256, 256);
    cast_wT<<<(128 * 256 + 255) / 256, 256, 0, stream>>>(w2_src, w2T, 256, 128, 256, 128);
    cast_wT<<<(128 * 128 + 255) / 256, 256, 0, stream>>>(fc1_w, fc1T, 128, 64, 128, 128);
    wv_kernel<<<4, 64, 0, stream>>>(w1_dst, a1_dst, vvec1, 256, 256);
    wv_kernel<<<4, 64, 0, stream>>>(w2_dst, a2_dst, vvec2, 256, 128);

    // h0 = relu(x @ lin_w + lin_b)   [bf16 out]; fused: aD1 = h0 @ vvec1
    mfma_gemm<<<dim3(MB, 2), 256, 0, stream>>>(x_bf, wlinT, lin_b, h0,
                                               vvec1, aD1, 320, 256, NN, 256, 3);

    // ---- GAT layer 1 (256 -> 256) ----
    // hsrc1 = h0 @ w1_src; fused: aS1 = hsrc1 @ a1_src
    mfma_gemm<<<dim3(MB, 2), 256, 0, stream>>>(h0, w1T, nullptr, hsrc1,
                                               a1_src, aS1, 256, 256, NN, 256, 2);
    // h1 = relu(aggregate + b1); fused: aD2 = h1 @ vvec2
    gat_agg_wave<64><<<(NN + 3) / 4, 256, 0, stream>>>(hsrc1, aS1, aD1, row_ptr,
                                                       csr_src, b1, h1, vvec2, aD2);

    // ---- GAT layer 2 (256 -> 128) ----
    // hsrc2 = h1 @ w2_src; fused: aS2 = hsrc2 @ a2_src
    mfma_gemm<<<dim3(MB, 1), 256, 0, stream>>>(h1, w2T, nullptr, hsrc2,
                                               a2_src, aS2, 256, 128, NN, 128, 2);
    gat_agg_wave<32><<<(NN + 7) / 8, 256, 0, stream>>>(hsrc2, aS2, aD2, row_ptr,
                                                       csr_src, b2, h2, nullptr, nullptr);

    // ---- fc1 + BN + relu + fc2 + log_softmax ----
    mfma_gemm<<<dim3(MB, 1), 256, 0, stream>>>(h2, fc1T, fc1_b, h3,
                                               nullptr, nullptr, 128, 64, NN, 64, 0);
    hipMemsetAsync(stats, 0, sizeof(float) * 128, stream);
    bn_stats<<<(NN + 255) / 256, 256, 0, stream>>>(h3, stats);
    bn_finalize<<<1, 64, 0, stream>>>(stats, bn_g, bn_b, ss);
    final_head<<<(NN + 3) / 4, 256, 0, stream>>>(h3, ss, fc2_w, fc2_b, out);
}

// Round 6
// 699.126 us; speedup vs baseline: 2.3245x; 1.0370x over previous
//
#include <hip/hip_runtime.h>
#include <hip/hip_bf16.h>
#include <cmath>

#define NN 100000
#define NE 800000
#define ETOT (NE + NN)
#define MP 100096            // 782 * 128, padded row count

#define SCHUNK 512
#define NBLK ((NN + SCHUNK - 1) / SCHUNK)   // 196

typedef __attribute__((ext_vector_type(8))) short bf16x8;
typedef __attribute__((ext_vector_type(4))) float f32x4;

__device__ inline void gl_lds16(const void* g, void* l) {
    __builtin_amdgcn_global_load_lds(
        (const __attribute__((address_space(1))) void*)g,
        (__attribute__((address_space(3))) void*)l, 16, 0, 0);
}

__device__ inline ushort f2bf(float f) {
    __hip_bfloat16 b = __float2bfloat16(f);
    return *(ushort*)&b;
}
__device__ inline uint pk2(float a, float b) {
    return (uint)f2bf(a) | ((uint)f2bf(b) << 16);
}

// ---------------- MFMA GEMM: C[M,N] = A[M,Kp] @ Bt[N,Kp]^T ------------------
// 128x128 tile, 4 waves, each wave 64x64 = 4x4 MFMA tiles of 16x16x32 bf16.
// flags: 1 = relu, 2 = bf16 output (else fp32)
// Optional fused row-dot: dotout[row] += sum_col v[row,col]*dotv[col]
__global__ __launch_bounds__(256)
void mfma_gemm(const __hip_bfloat16* __restrict__ Abf,
               const __hip_bfloat16* __restrict__ Btbf,
               const float* __restrict__ bias, void* __restrict__ out,
               const float* __restrict__ dotv, float* __restrict__ dotout,
               int Kp, int ldc, int Mstore, int Nstore, int flags)
{
    __shared__ __align__(16) short As[128 * 32];
    __shared__ __align__(16) short Bs[128 * 32];
    const short* A  = (const short*)Abf;
    const short* Bt = (const short*)Btbf;

    const int tid  = threadIdx.x;
    const int lane = tid & 63;
    const int wv   = tid >> 6;
    const int wr   = (wv >> 1) * 64;
    const int wc   = (wv & 1) * 64;
    const int quad = lane >> 4;
    const int l16  = lane & 15;
    const long bm = (long)blockIdx.x * 128;
    const long bn = (long)blockIdx.y * 128;

    const int r0 = tid >> 2;
    const int c0 = (tid & 3) ^ ((r0 >> 1) & 3);
    const int r1 = r0 + 64;
    const int c1 = (tid & 3) ^ ((r1 >> 1) & 3);
    const short* a_g0 = A + (bm + r0) * (long)Kp + c0 * 8;
    const short* a_g1 = A + (bm + r1) * (long)Kp + c1 * 8;
    const short* b_g0 = Bt + (bn + r0) * (long)Kp + c0 * 8;
    const short* b_g1 = Bt + (bn + r1) * (long)Kp + c1 * 8;
    short* a_l0 = &As[tid * 8];
    short* a_l1 = &As[(tid + 256) * 8];
    short* b_l0 = &Bs[tid * 8];
    short* b_l1 = &Bs[(tid + 256) * 8];

    f32x4 acc[4][4] = {};
    const int xr = (quad ^ ((l16 >> 1) & 3)) * 8;

    for (int k0 = 0; k0 < Kp; k0 += 32) {
        gl_lds16(a_g0 + k0, a_l0);
        gl_lds16(a_g1 + k0, a_l1);
        gl_lds16(b_g0 + k0, b_l0);
        gl_lds16(b_g1 + k0, b_l1);
        __syncthreads();

        bf16x8 af[4], bf[4];
#pragma unroll
        for (int i = 0; i < 4; i++)
            af[i] = *(const bf16x8*)&As[(wr + i * 16 + l16) * 32 + xr];
#pragma unroll
        for (int j = 0; j < 4; j++)
            bf[j] = *(const bf16x8*)&Bs[(wc + j * 16 + l16) * 32 + xr];
#pragma unroll
        for (int i = 0; i < 4; i++)
#pragma unroll
            for (int j = 0; j < 4; j++)
                acc[i][j] = __builtin_amdgcn_mfma_f32_16x16x32_bf16(
                    af[i], bf[j], acc[i][j], 0, 0, 0);
        __syncthreads();
    }

    __hip_bfloat16* outb = (__hip_bfloat16*)out;
    float* outf = (float*)out;
    float dp[16];
#pragma unroll
    for (int t = 0; t < 16; t++) dp[t] = 0.f;

#pragma unroll
    for (int i = 0; i < 4; i++) {
        long row_base = bm + wr + i * 16 + quad * 4;
#pragma unroll
        for (int j = 0; j < 4; j++) {
            long col = bn + wc + j * 16 + l16;
            if (col >= Nstore) continue;
            float bv = bias ? bias[col] : 0.f;
            float dv = dotout ? dotv[col] : 0.f;
#pragma unroll
            for (int r = 0; r < 4; r++) {
                long row = row_base + r;
                float v = acc[i][j][r] + bv;
                if (flags & 1) v = fmaxf(v, 0.f);
                dp[i * 4 + r] = fmaf(v, dv, dp[i * 4 + r]);
                if (row >= Mstore) continue;
                if (flags & 2) outb[row * ldc + col] = __float2bfloat16(v);
                else           outf[row * ldc + col] = v;
            }
        }
    }

    if (dotout) {
#pragma unroll
        for (int t = 0; t < 16; t++) {
            float s = dp[t];
            s += __shfl_xor(s, 1); s += __shfl_xor(s, 2);
            s += __shfl_xor(s, 4); s += __shfl_xor(s, 8);
            if (l16 == 0) {
                long row = bm + wr + (t >> 2) * 16 + quad * 4 + (t & 3);
                if (row < Mstore) atomicAdd(&dotout[row], s);
            }
        }
    }
}

// ---------------- casts ----------------
// x [NN,300] fp32 -> [MP,320] bf16 zero-padded. 8 cols/thread, 40 thr/row.
// float4 x2 loads (32 B) -> uint4 store (16 B).
__global__ __launch_bounds__(256)
void cast_x_vec(const float* __restrict__ x, __hip_bfloat16* __restrict__ xb)
{
    const int idx = blockIdx.x * 256 + threadIdx.x;
    if (idx >= MP * 40) return;
    const int row = idx / 40;
    const int c8  = (idx % 40) * 8;
    uint4 v;
    if (row < NN && c8 + 8 <= 300) {
        const float* xp = x + (size_t)row * 300 + c8;
        float4 f0 = *(const float4*)xp;
        float4 f1 = *(const float4*)(xp + 4);
        v.x = pk2(f0.x, f0.y); v.y = pk2(f0.z, f0.w);
        v.z = pk2(f1.x, f1.y); v.w = pk2(f1.z, f1.w);
    } else {
        float f[8];
#pragma unroll
        for (int k = 0; k < 8; k++)
            f[k] = (row < NN && c8 + k < 300) ? x[(size_t)row * 300 + c8 + k] : 0.f;
        v.x = pk2(f[0], f[1]); v.y = pk2(f[2], f[3]);
        v.z = pk2(f[4], f[5]); v.w = pk2(f[6], f[7]);
    }
    *(uint4*)((ushort*)xb + (size_t)row * 320 + c8) = v;
}

__global__ void cast_wT(const float* __restrict__ w, __hip_bfloat16* __restrict__ wt,
                        int K, int N, int Kp, int Np)
{
    int idx = blockIdx.x * 256 + threadIdx.x;
    if (idx >= Np * Kp) return;
    int n = idx / Kp, k = idx % Kp;
    float v = (n < N && k < K) ? w[(size_t)k * N + n] : 0.f;
    wt[idx] = __float2bfloat16(v);
}

// ---------------- CSR build ----------------
__global__ void count_edges(const int* __restrict__ ei, int* __restrict__ counts)
{
    int e = blockIdx.x * blockDim.x + threadIdx.x;
    if (e >= ETOT) return;
    int d = (e < NE) ? ei[NE + e] : (e - NE);
    atomicAdd(&counts[d], 1);
}

__global__ __launch_bounds__(256)
void scan_partial(const int* __restrict__ counts, int* __restrict__ blk)
{
    __shared__ int sh[256];
    const int tid = threadIdx.x;
    const int base = blockIdx.x * SCHUNK + tid * 2;
    int c0 = (base < NN)     ? counts[base]     : 0;
    int c1 = (base + 1 < NN) ? counts[base + 1] : 0;
    sh[tid] = c0 + c1;
    __syncthreads();
    for (int off = 128; off; off >>= 1) {
        if (tid < off) sh[tid] += sh[tid + off];
        __syncthreads();
    }
    if (tid == 0) blk[blockIdx.x] = sh[0];
}

__global__ __launch_bounds__(256)
void scan_blocks(int* __restrict__ blk)
{
    __shared__ int sh[256];
    const int tid = threadIdx.x;
    int v = (tid < NBLK) ? blk[tid] : 0;
    sh[tid] = v;
    __syncthreads();
    for (int off = 1; off < 256; off <<= 1) {
        int u = (tid >= off) ? sh[tid - off] : 0;
        __syncthreads();
        sh[tid] += u;
        __syncthreads();
    }
    if (tid < NBLK) blk[tid] = sh[tid] - v;   // exclusive
}

__global__ __launch_bounds__(256)
void scan_fill(const int* __restrict__ counts, const int* __restrict__ blk,
               int* __restrict__ row_ptr, int* __restrict__ cursor)
{
    __shared__ int sh[256];
    const int tid = threadIdx.x;
    const int i0 = blockIdx.x * SCHUNK + tid * 2;
    int c0 = (i0 < NN)     ? counts[i0]     : 0;
    int c1 = (i0 + 1 < NN) ? counts[i0 + 1] : 0;
    int s = c0 + c1;
    sh[tid] = s;
    __syncthreads();
    for (int off = 1; off < 256; off <<= 1) {
        int u = (tid >= off) ? sh[tid - off] : 0;
        __syncthreads();
        sh[tid] += u;
        __syncthreads();
    }
    int pre = sh[tid] - s + blk[blockIdx.x];
    if (i0 < NN)     { row_ptr[i0] = pre;          cursor[i0] = pre; }
    if (i0 + 1 < NN) { row_ptr[i0 + 1] = pre + c0; cursor[i0 + 1] = pre + c0; }
    if (blockIdx.x == 0 && tid == 0) row_ptr[NN] = ETOT;
}

__global__ void fill_edges(const int* __restrict__ ei, int* __restrict__ cursor,
                           int* __restrict__ csr_src)
{
    int e = blockIdx.x * blockDim.x + threadIdx.x;
    if (e >= ETOT) return;
    int s, d;
    if (e < NE) { s = ei[e]; d = ei[NE + e]; }
    else        { s = e - NE; d = s; }
    int pos = atomicAdd(&cursor[d], 1);
    csr_src[pos] = s;
}

// ---------------- small matvec helper (weights only) ----------------
__global__ void wv_kernel(const float* __restrict__ w, const float* __restrict__ a,
                          float* __restrict__ v, int Cin, int Cout)
{
    int i = blockIdx.x * blockDim.x + threadIdx.x;
    if (i >= Cin) return;
    float s = 0.f;
    for (int j = 0; j < Cout; j++) s = fmaf(w[(size_t)i * Cout + j], a[j], s);
    v[i] = s;
}

// ---------------- GAT attention + aggregation ------------------------------
// LPN lanes per node, 4 channels per lane (C = LPN*4). (w,src) staged in
// per-wave LDS; edges processed 4 at a time (4 gathers in flight).
template<int LPN>
__global__ __launch_bounds__(256)
void gat_agg_wave(const __hip_bfloat16* __restrict__ hsrc,
                  const float* __restrict__ a_s,
                  const float* __restrict__ a_d,
                  const int* __restrict__ row_ptr,
                  const int* __restrict__ csr_src,
                  const float* __restrict__ bias,
                  __hip_bfloat16* __restrict__ outh,
                  const float* __restrict__ dotv,
                  float* __restrict__ dotout)
{
    const int C = LPN * 4;
    const int NPB = 256 / LPN;               // nodes per block
    __shared__ __align__(16) float2 ws_sh[NPB][LPN];

    const int tid  = threadIdx.x;
    const int slot = tid / LPN;
    const int sub  = tid % LPN;
    const int n = blockIdx.x * NPB + slot;
    if (n >= NN) return;

    const int start = row_ptr[n];
    const int deg = row_ptr[n + 1] - start;
    const float a_dn = a_d[n];
    const ushort* hp = (const ushort*)hsrc;

    float M = -3e30f, S = 0.f;
    float acc0 = 0.f, acc1 = 0.f, acc2 = 0.f, acc3 = 0.f;

    for (int c0 = 0; c0 < deg; c0 += LPN) {
        const int cnt = min(LPN, deg - c0);
        int sj = 0;
        float e = -3e30f;
        if (sub < cnt) {
            sj = csr_src[start + c0 + sub];
            float t = a_s[sj] + a_dn;
            e = (t >= 0.f) ? t : 0.2f * t;
        }
        float cm = e;
#pragma unroll
        for (int off = LPN / 2; off; off >>= 1) cm = fmaxf(cm, __shfl_xor(cm, off));
        float newM = fmaxf(M, cm);
        float w = (sub < cnt) ? __expf(e - newM) : 0.f;
        float cs = w;
#pragma unroll
        for (int off = LPN / 2; off; off >>= 1) cs += __shfl_xor(cs, off);
        float scale = __expf(M - newM);      // 0 on first chunk, 1 if M unchanged
        S = S * scale + cs;
        acc0 *= scale; acc1 *= scale; acc2 *= scale; acc3 *= scale;
        M = newM;

        ws_sh[slot][sub] = make_float2(w, __int_as_float(sj));
        const int cnt4 = (cnt + 3) & ~3;
        const ushort* hpl = hp + sub * 4;
        for (int j = 0; j < cnt4; j += 4) {
            float4 p0 = *(const float4*)&ws_sh[slot][j];
            float4 p1 = *(const float4*)&ws_sh[slot][j + 2];
            const ushort* r0 = hpl + (size_t)__float_as_int(p0.y) * C;
            const ushort* r1 = hpl + (size_t)__float_as_int(p0.w) * C;
            const ushort* r2 = hpl + (size_t)__float_as_int(p1.y) * C;
            const ushort* r3 = hpl + (size_t)__float_as_int(p1.w) * C;
            uint2 u0 = *(const uint2*)r0;
            uint2 u1 = *(const uint2*)r1;
            uint2 u2 = *(const uint2*)r2;
            uint2 u3 = *(const uint2*)r3;
            acc0 = fmaf(p0.x, __uint_as_float(u0.x << 16), acc0);
            acc1 = fmaf(p0.x, __uint_as_float(u0.x & 0xffff0000u), acc1);
            acc2 = fmaf(p0.x, __uint_as_float(u0.y << 16), acc2);
            acc3 = fmaf(p0.x, __uint_as_float(u0.y & 0xffff0000u), acc3);
            acc0 = fmaf(p0.z, __uint_as_float(u1.x << 16), acc0);
            acc1 = fmaf(p0.z, __uint_as_float(u1.x & 0xffff0000u), acc1);
            acc2 = fmaf(p0.z, __uint_as_float(u1.y << 16), acc2);
            acc3 = fmaf(p0.z, __uint_as_float(u1.y & 0xffff0000u), acc3);
            acc0 = fmaf(p1.x, __uint_as_float(u2.x << 16), acc0);
            acc1 = fmaf(p1.x, __uint_as_float(u2.x & 0xffff0000u), acc1);
            acc2 = fmaf(p1.x, __uint_as_float(u2.y << 16), acc2);
            acc3 = fmaf(p1.x, __uint_as_float(u2.y & 0xffff0000u), acc3);
            acc0 = fmaf(p1.z, __uint_as_float(u3.x << 16), acc0);
            acc1 = fmaf(p1.z, __uint_as_float(u3.x & 0xffff0000u), acc1);
            acc2 = fmaf(p1.z, __uint_as_float(u3.y << 16), acc2);
            acc3 = fmaf(p1.z, __uint_as_float(u3.y & 0xffff0000u), acc3);
        }
    }

    float inv = 1.f / (S + 1e-16f);
    float o0 = fmaxf(acc0 * inv + bias[sub * 4 + 0], 0.f);
    float o1 = fmaxf(acc1 * inv + bias[sub * 4 + 1], 0.f);
    float o2 = fmaxf(acc2 * inv + bias[sub * 4 + 2], 0.f);
    float o3 = fmaxf(acc3 * inv + bias[sub * 4 + 3], 0.f);

    ushort4 v;
    v.x = f2bf(o0); v.y = f2bf(o1); v.z = f2bf(o2); v.w = f2bf(o3);
    *(ushort4*)((ushort*)outh + (size_t)n * C + sub * 4) = v;

    if (dotout) {
        float dp = o0 * dotv[sub * 4 + 0] + o1 * dotv[sub * 4 + 1]
                 + o2 * dotv[sub * 4 + 2] + o3 * dotv[sub * 4 + 3];
#pragma unroll
        for (int off = LPN / 2; off; off >>= 1) dp += __shfl_xor(dp, off);
        if (sub == 0) dotout[n] = dp;
    }
}

// ---------------- BatchNorm stats + finalize ----------------
__global__ __launch_bounds__(256)
void bn_stats(const float* __restrict__ h, float* __restrict__ stats)
{
    int col = threadIdx.x & 63;
    int rg = threadIdx.x >> 6;
    int r0 = blockIdx.x * 256;
    int r1 = min(r0 + 256, NN);
    float s = 0.f, s2 = 0.f;
    for (int r = r0 + rg; r < r1; r += 4) {
        float v = h[(size_t)r * 64 + col];
        s += v; s2 += v * v;
    }
    __shared__ float sh[2][4][64];
    sh[0][rg][col] = s; sh[1][rg][col] = s2;
    __syncthreads();
    if (rg == 0) {
        s  = sh[0][0][col] + sh[0][1][col] + sh[0][2][col] + sh[0][3][col];
        s2 = sh[1][0][col] + sh[1][1][col] + sh[1][2][col] + sh[1][3][col];
        atomicAdd(&stats[col], s);
        atomicAdd(&stats[64 + col], s2);
    }
}

__global__ void bn_finalize(const float* __restrict__ stats,
                            const float* __restrict__ g, const float* __restrict__ b,
                            float* __restrict__ ss)
{
    int c = threadIdx.x;
    float mu = stats[c] / (float)NN;
    float var = stats[64 + c] / (float)NN - mu * mu;
    float rs = rsqrtf(var + 1e-5f);
    float sc = rs * g[c];
    ss[c] = sc;
    ss[64 + c] = b[c] - mu * sc;
}

__global__ __launch_bounds__(256)
void final_head(const float* __restrict__ h3, const float* __restrict__ ss,
                const float* __restrict__ fc2_w, const float* __restrict__ fc2_b,
                float* __restrict__ out)
{
    int lane = threadIdx.x & 63;
    int n = blockIdx.x * 4 + (threadIdx.x >> 6);
    if (n >= NN) return;
    float y = h3[(size_t)n * 64 + lane];
    y = fmaxf(y * ss[lane] + ss[64 + lane], 0.f);
    float z[4];
#pragma unroll
    for (int o = 0; o < 4; o++) {
        float p = y * fc2_w[lane * 4 + o];
#pragma unroll
        for (int off = 32; off; off >>= 1) p += __shfl_xor(p, off);
        z[o] = p + fc2_b[o];
    }
    float mx = fmaxf(fmaxf(z[0], z[1]), fmaxf(z[2], z[3]));
    float lse = mx + logf(expf(z[0] - mx) + expf(z[1] - mx) +
                          expf(z[2] - mx) + expf(z[3] - mx));
    if (lane < 4) out[(size_t)n * 4 + lane] = z[lane] - lse;
}

// ---------------- launch ----------------
extern "C" void kernel_launch(void* const* d_in, const int* in_sizes, int n_in,
                              void* d_out, int out_size, void* d_ws, size_t ws_size,
                              hipStream_t stream)
{
    const float* x      = (const float*)d_in[0];
    const int*   ei     = (const int*)d_in[1];
    const float* lin_w  = (const float*)d_in[2];
    const float* lin_b  = (const float*)d_in[3];
    const float* w1_src = (const float*)d_in[4];
    const float* w1_dst = (const float*)d_in[5];
    const float* a1_src = (const float*)d_in[6];
    const float* a1_dst = (const float*)d_in[7];
    const float* b1     = (const float*)d_in[8];
    const float* w2_src = (const float*)d_in[9];
    const float* w2_dst = (const float*)d_in[10];
    const float* a2_src = (const float*)d_in[11];
    const float* a2_dst = (const float*)d_in[12];
    const float* b2     = (const float*)d_in[13];
    const float* fc1_w  = (const float*)d_in[14];
    const float* fc1_b  = (const float*)d_in[15];
    const float* bn_g   = (const float*)d_in[16];
    const float* bn_b   = (const float*)d_in[17];
    const float* fc2_w  = (const float*)d_in[18];
    const float* fc2_b  = (const float*)d_in[19];
    float* out = (float*)d_out;

    // -------- workspace layout (region reuse) --------
    char* p = (char*)d_ws;
    auto alloc = [&](size_t bytes) { char* r = p; p += (bytes + 255) & ~(size_t)255; return r; };
    char* R1 = alloc((size_t)MP * 320 * 2);   // x_bf  -> hsrc1
    char* R2 = alloc((size_t)MP * 256 * 2);   // h0    -> hsrc2 | h2
    char* R3 = alloc((size_t)MP * 256 * 2);   // h1    -> h3(f32)
    __hip_bfloat16* wlinT = (__hip_bfloat16*)alloc(256 * 320 * 2);
    __hip_bfloat16* w1T   = (__hip_bfloat16*)alloc(256 * 256 * 2);
    __hip_bfloat16* w2T   = (__hip_bfloat16*)alloc(128 * 256 * 2);
    __hip_bfloat16* fc1T  = (__hip_bfloat16*)alloc(128 * 128 * 2);
    float* avec  = (float*)alloc((size_t)NN * 4 * 4);   // aS1|aD1|aS2|aD2 contiguous
    float* aS1 = avec;
    float* aD1 = avec + NN;
    float* aS2 = avec + 2 * (size_t)NN;
    float* aD2 = avec + 3 * (size_t)NN;
    float* vvec1 = (float*)alloc(256 * 4);
    float* vvec2 = (float*)alloc(256 * 4);
    float* ss    = (float*)alloc(128 * 4);
    float* stats = (float*)alloc(128 * 4);
    int* row_ptr = (int*)alloc((size_t)(NN + 1) * 4);
    int* cursor  = (int*)alloc((size_t)(NN + 1) * 4);
    int* counts  = (int*)alloc((size_t)NN * 4);
    int* blk     = (int*)alloc(256 * 4);
    int* csr_src = (int*)alloc((size_t)ETOT * 4);

    __hip_bfloat16* x_bf  = (__hip_bfloat16*)R1;
    __hip_bfloat16* hsrc1 = (__hip_bfloat16*)R1;
    __hip_bfloat16* h0    = (__hip_bfloat16*)R2;
    __hip_bfloat16* hsrc2 = (__hip_bfloat16*)R2;
    __hip_bfloat16* h2    = (__hip_bfloat16*)(R2 + (size_t)MP * 128 * 2);
    __hip_bfloat16* h1    = (__hip_bfloat16*)R3;
    float*          h3    = (float*)R3;

    const int eb = (ETOT + 255) / 256;
    const int MB = MP / 128;   // 782

    // zero the atomic dot outputs (contiguous block, fully covered)
    hipMemsetAsync(avec, 0, sizeof(float) * NN * 4, stream);

    // CSR build (parallel 3-phase scan; reused by both GAT layers)
    hipMemsetAsync(counts, 0, sizeof(int) * NN, stream);
    count_edges<<<eb, 256, 0, stream>>>(ei, counts);
    scan_partial<<<NBLK, 256, 0, stream>>>(counts, blk);
    scan_blocks<<<1, 256, 0, stream>>>(blk);
    scan_fill<<<NBLK, 256, 0, stream>>>(counts, blk, row_ptr, cursor);
    fill_edges<<<eb, 256, 0, stream>>>(ei, cursor, csr_src);

    // casts + attention weight matvecs
    cast_x_vec<<<(MP * 40 + 255) / 256, 256, 0, stream>>>(x, x_bf);
    cast_wT<<<(256 * 320 + 255) / 256, 256, 0, stream>>>(lin_w, wlinT, 300, 256, 320, 256);
    cast_wT<<<(256 * 256 + 255) / 256, 256, 0, stream>>>(w1_src, w1T, 256, 256, 256, 256);
    cast_wT<<<(128 * 256 + 255) / 256, 256, 0, stream>>>(w2_src, w2T, 256, 128, 256, 128);
    cast_wT<<<(128 * 128 + 255) / 256, 256, 0, stream>>>(fc1_w, fc1T, 128, 64, 128, 128);
    wv_kernel<<<4, 64, 0, stream>>>(w1_dst, a1_dst, vvec1, 256, 256);
    wv_kernel<<<4, 64, 0, stream>>>(w2_dst, a2_dst, vvec2, 256, 128);

    // h0 = relu(x @ lin_w + lin_b)   [bf16 out]; fused: aD1 = h0 @ vvec1
    mfma_gemm<<<dim3(MB, 2), 256, 0, stream>>>(x_bf, wlinT, lin_b, h0,
                                               vvec1, aD1, 320, 256, NN, 256, 3);

    // ---- GAT layer 1 (256 -> 256) ----
    mfma_gemm<<<dim3(MB, 2), 256, 0, stream>>>(h0, w1T, nullptr, hsrc1,
                                               a1_src, aS1, 256, 256, NN, 256, 2);
    gat_agg_wave<64><<<(NN + 3) / 4, 256, 0, stream>>>(hsrc1, aS1, aD1, row_ptr,
                                                       csr_src, b1, h1, vvec2, aD2);

    // ---- GAT layer 2 (256 -> 128) ----
    mfma_gemm<<<dim3(MB, 1), 256, 0, stream>>>(h1, w2T, nullptr, hsrc2,
                                               a2_src, aS2, 256, 128, NN, 128, 2);
    gat_agg_wave<32><<<(NN + 7) / 8, 256, 0, stream>>>(hsrc2, aS2, aD2, row_ptr,
                                                       csr_src, b2, h2, nullptr, nullptr);

    // ---- fc1 + BN + relu + fc2 + log_softmax ----
    mfma_gemm<<<dim3(MB, 1), 256, 0, stream>>>(h2, fc1T, fc1_b, h3,
                                               nullptr, nullptr, 128, 64, NN, 64, 0);
    hipMemsetAsync(stats, 0, sizeof(float) * 128, stream);
    bn_stats<<<(NN + 255) / 256, 256, 0, stream>>>(h3, stats);
    bn_finalize<<<1, 64, 0, stream>>>(stats, bn_g, bn_b, ss);
    final_head<<<(NN + 3) / 4, 256, 0, stream>>>(h3, ss, fc2_w, fc2_b, out);
}